// Round 9
// baseline (456.062 us; speedup 1.0000x reference)
//
#include <hip/hip_runtime.h>
#include <math.h>

static constexpr int N_NODES = 50000;
static constexpr int N_EDGES = 800000;
static constexpr int DMODEL  = 128;
static constexpr int MTILES  = N_NODES / 16;   // 3125 exactly
static constexpr int CAPLOG  = 6;              // 64 slots/node; max degree ~40 (Poisson(16))
static constexpr int ESPLIT  = 400384;         // 391 blocks * 1024 edges

typedef __attribute__((ext_vector_type(8))) short short8;   // 8 bf16 (4 VGPRs)
typedef __attribute__((ext_vector_type(4))) float float4v;  // 4 fp32 acc

__device__ __forceinline__ unsigned short f2bf(float f) {
    unsigned u = __builtin_bit_cast(unsigned, f);
    u += 0x7fffu + ((u >> 16) & 1u);
    return (unsigned short)(u >> 16);
}
__device__ __forceinline__ float bf2f(unsigned short b) {
    unsigned u = ((unsigned)b) << 16;
    return __builtin_bit_cast(float, u);
}

// ---------------------------------------------------------------------------
// Weight prep: fp32 [K][N] row-major -> bf16 MFMA B-fragment order.
//   idx = (nt*ksteps + s)*512 + quad*128 + c*8 + j   (nt=n>>4, c=n&15, s=k>>5)
// ---------------------------------------------------------------------------
struct PrepSeg { const float* src; int K; int N; int dstOff; };
struct PrepArgs { PrepSeg seg[13]; };

__global__ void prep_kernel(PrepArgs pa, unsigned short* wf)
{
    PrepSeg sg = pa.seg[blockIdx.y];
    int e = blockIdx.x * 256 + threadIdx.x;
    int total = sg.K * sg.N;
    if (e >= total) return;
    int n = e % sg.N;
    int k = e / sg.N;
    int ks = sg.K >> 5;
    int nt = n >> 4, c = n & 15, s = k >> 5, q = (k >> 3) & 3, jj = k & 7;
    int di = sg.dstOff + (nt * ks + s) * 512 + q * 128 + c * 8 + jj;
    wf[di] = f2bf(sg.src[e]);
}

// ---------------------------------------------------------------------------
// Padded one-pass bucket build body: rank = atomicAdd(counts[dst]), slot into
// eslot[dst*64 + rank]. Fused into GEMM dispatches (extra blockIdx.y
// partition) so the atomic latency hides under compute-heavy work.
// ---------------------------------------------------------------------------
__device__ __forceinline__ void scatter_body(
    const int* __restrict__ src, const int* __restrict__ dst,
    int* counts, int* eslot, int ebeg, int eend)
{
    int base = ebeg + blockIdx.x * 1024 + threadIdx.x;
    int d[4], s[4];
    bool v[4];
#pragma unroll
    for (int k = 0; k < 4; ++k) {
        int e = base + k * 256;
        v[k] = e < eend;
        int ec = v[k] ? e : ebeg;
        d[k] = dst[ec];
        s[k] = src[ec];
    }
#pragma unroll
    for (int k = 0; k < 4; ++k) {
        if (v[k]) {
            int r = atomicAdd(&counts[d[k]], 1);
            eslot[(d[k] << CAPLOG) + r] = s[k];
        }
    }
}

// ---------------------------------------------------------------------------
// MFMA GEMM body with LDS-staged B (R8: proven win — B-reload from L2 was the
// first-order cost; staging cuts it 4x per block). For NT*KSTEPS<=32 the
// B-frags are then held in registers; for larger panels (fused f2+LN: 8x8=64
// frags = 256 VGPRs) the MFMA loop reads B per-use from LDS (ds_read_b128,
// hidden under MFMA) to avoid guaranteed spill.
// Wave = 16-row m-tile x NT*16 cols, 2 m-tiles/wave at GX=391.
// EPI: 0=bias, 1=bias+relu, 2=bias+residual, 3=bias+residual+LayerNorm
// (EPI 3 requires NT*16==128, colBase==0).
// ---------------------------------------------------------------------------
template<int KSTEPS, int NT, int EPI, bool AF32, bool WRF, bool WRB>
__device__ __forceinline__ void gemm_body(
    const void* __restrict__ Ap, const unsigned short* __restrict__ Wfc,
    const float* __restrict__ bias, const float* res,
    float* Cf, unsigned short* Cb,
    const float* __restrict__ lnw, const float* __restrict__ lnb,
    int ldA, int ldC, int mtiles, int colBase)
{
    const int lane = threadIdx.x & 63;
    const int c = lane & 15;
    const int q = lane >> 4;

    // ---- cooperative B-panel stage ----
    __shared__ unsigned short smB[NT * KSTEPS * 512];
    {
        const int totalVec = NT * KSTEPS * 64;   // uint4 count
        const uint4* gsrc = (const uint4*)Wfc;
        uint4* sdst = (uint4*)smB;
#pragma unroll
        for (int i = threadIdx.x; i < totalVec; i += 256)
            sdst[i] = gsrc[i];
    }
    __syncthreads();

    constexpr bool BREG = (NT * KSTEPS) <= 32;
    short8 bfrag[BREG ? NT * KSTEPS : 1];
    if constexpr (BREG) {
#pragma unroll
        for (int nt = 0; nt < NT; ++nt)
#pragma unroll
            for (int s = 0; s < KSTEPS; ++s)
                bfrag[nt * KSTEPS + s] = *(const short8*)(smB + (nt * KSTEPS + s) * 512 + lane * 8);
    }

    float bb[NT];
#pragma unroll
    for (int nt = 0; nt < NT; ++nt)
        bb[nt] = bias ? bias[colBase + nt * 16 + c] : 0.f;

    float lw[NT], lb[NT];
    if (EPI == 3) {
#pragma unroll
        for (int nt = 0; nt < NT; ++nt) {
            lw[nt] = lnw[nt * 16 + c];
            lb[nt] = lnb[nt * 16 + c];
        }
    }

    const int wid = blockIdx.x * 4 + (threadIdx.x >> 6);
    const int nw  = gridDim.x * 4;

    for (int mt = wid; mt < mtiles; mt += nw) {
        const int row0 = mt * 16;
        short8 afrag[KSTEPS];
        if (AF32) {
            const float* A32 = (const float*)Ap;
#pragma unroll
            for (int s = 0; s < KSTEPS; ++s) {
                const float4* p = (const float4*)(A32 + (size_t)(row0 + c) * ldA + s * 32 + q * 8);
                float4 x0 = p[0], x1 = p[1];
                short8 a;
                a[0] = (short)f2bf(x0.x); a[1] = (short)f2bf(x0.y);
                a[2] = (short)f2bf(x0.z); a[3] = (short)f2bf(x0.w);
                a[4] = (short)f2bf(x1.x); a[5] = (short)f2bf(x1.y);
                a[6] = (short)f2bf(x1.z); a[7] = (short)f2bf(x1.w);
                afrag[s] = a;
            }
        } else {
            const unsigned short* Ab = (const unsigned short*)Ap;
#pragma unroll
            for (int s = 0; s < KSTEPS; ++s)
                afrag[s] = *(const short8*)(Ab + (size_t)(row0 + c) * ldA + s * 32 + q * 8);
        }

        float4v acc[NT];
#pragma unroll
        for (int nt = 0; nt < NT; ++nt) acc[nt] = (float4v)0.f;
#pragma unroll
        for (int s = 0; s < KSTEPS; ++s)
#pragma unroll
            for (int nt = 0; nt < NT; ++nt) {
                short8 b;
                if constexpr (BREG) b = bfrag[nt * KSTEPS + s];
                else b = *(const short8*)(smB + (nt * KSTEPS + s) * 512 + lane * 8);
                acc[nt] = __builtin_amdgcn_mfma_f32_16x16x32_bf16(afrag[s], b, acc[nt], 0, 0, 0);
            }

        // epilogue: C row = row0 + q*4 + r, col = colBase + nt*16 + c
#pragma unroll
        for (int nt = 0; nt < NT; ++nt) {
            const int col = colBase + nt * 16 + c;
#pragma unroll
            for (int r = 0; r < 4; ++r) {
                const int grow = row0 + q * 4 + r;
                float v = acc[nt][r] + bb[nt];
                if (EPI == 2 || EPI == 3) v += res[(size_t)grow * ldC + col];
                if (EPI == 1) v = fmaxf(v, 0.f);
                acc[nt][r] = v;
            }
        }

        if (EPI == 3) {
            // full-row LayerNorm: reduce over 16 lanes of quad (cols) x NT regs
#pragma unroll
            for (int r = 0; r < 4; ++r) {
                float s = 0.f, ss = 0.f;
#pragma unroll
                for (int nt = 0; nt < NT; ++nt) {
                    float v = acc[nt][r];
                    s += v; ss = fmaf(v, v, ss);
                }
#pragma unroll
                for (int o = 1; o < 16; o <<= 1) {
                    s  += __shfl_xor(s, o, 64);
                    ss += __shfl_xor(ss, o, 64);
                }
                float m   = s * (1.0f / 128.0f);
                float var = ss * (1.0f / 128.0f) - m * m;
                float rs  = rsqrtf(var + 1e-5f);
                const int grow = row0 + q * 4 + r;
#pragma unroll
                for (int nt = 0; nt < NT; ++nt) {
                    float v = (acc[nt][r] - m) * rs * lw[nt] + lb[nt];
                    if (WRF) Cf[(size_t)grow * ldC + nt * 16 + c] = v;
                    if (WRB) Cb[(size_t)grow * ldC + nt * 16 + c] = f2bf(v);
                }
            }
        } else {
#pragma unroll
            for (int nt = 0; nt < NT; ++nt) {
                const int col = colBase + nt * 16 + c;
#pragma unroll
                for (int r = 0; r < 4; ++r) {
                    const int grow = row0 + q * 4 + r;
                    if (WRF) Cf[(size_t)grow * ldC + col] = acc[nt][r];
                    if (WRB) Cb[(size_t)grow * ldC + col] = f2bf(acc[nt][r]);
                }
            }
        }
    }
}

template<int KSTEPS, int NT, int EPI, bool AF32, bool WRF, bool WRB>
__global__ __launch_bounds__(256, 2)
void mfma_gemm(const void* __restrict__ Ap, const unsigned short* __restrict__ Wf,
               const float* __restrict__ bias, const float* res,
               float* Cf, unsigned short* Cb,
               const float* __restrict__ lnw, const float* __restrict__ lnb,
               int ldA, int ldC, int mtiles)
{
    const int colBase = blockIdx.y * NT * 16;
    const unsigned short* Wfc = Wf + (size_t)blockIdx.y * NT * KSTEPS * 512;
    gemm_body<KSTEPS, NT, EPI, AF32, WRF, WRB>(
        Ap, Wfc, bias, res, Cf, Cb, lnw, lnb, ldA, ldC, mtiles, colBase);
}

// Embedding GEMM fused with scatter half 1 (blockIdx.y==1 -> scatter).
__global__ __launch_bounds__(256, 2)
void emb_sc_gemm(const float* __restrict__ A, const unsigned short* __restrict__ Wf,
                 float* Cf, unsigned short* Cb, int mtiles,
                 const int* __restrict__ src, const int* __restrict__ dst,
                 int* counts, int* eslot, int ebeg, int eend)
{
    if (blockIdx.y == 1) {
        scatter_body(src, dst, counts, eslot, ebeg, eend);
        return;
    }
    gemm_body<4, 8, 0, true, true, true>(
        A, Wf, nullptr, nullptr, Cf, Cb, nullptr, nullptr, 128, 128, mtiles, 0);
}

// Q/K/V fused + scatter half 2 (blockIdx.y==3 -> scatter on layer 0).
// K and V write into the interleaved kv buffer [node][K 0..127 | V 128..255].
struct QkvPtrs { const float* bias[3]; unsigned short* out[3]; int ldc[3]; };

__global__ __launch_bounds__(256, 2)
void qkv_sc_gemm(const unsigned short* __restrict__ A, const unsigned short* __restrict__ WfBase,
                 QkvPtrs ptrs, int mtiles,
                 const int* __restrict__ src, const int* __restrict__ dst,
                 int* counts, int* eslot, int ebeg, int eend)
{
    if (blockIdx.y == 3) {
        scatter_body(src, dst, counts, eslot, ebeg, eend);
        return;
    }
    const int sel = blockIdx.y;
    gemm_body<4, 8, 0, false, false, true>(
        A, WfBase + (size_t)sel * 32768, ptrs.bias[sel], nullptr,
        nullptr, ptrs.out[sel], nullptr, nullptr, 128, ptrs.ldc[sel], mtiles, 0);
}

// ---------------------------------------------------------------------------
// Attention aggregation (R4 form — measured best: 55.7us, VGPR 32, occ 67%).
// 16-lanes-per-edge, 8 edges/iter. TLP at ~8 waves/SIMD hides gather latency;
// deeper per-wave unroll/prefetch measured WORSE (R2: 16-edge, R5: dbuf).
//   wave = one dst node; quarter g=lane>>4 owns edge slots g and g+4; lane
//   li=lane&15 covers dims 8*li..8*li+7 (head = li>>1). K|V interleaved rows:
//   each edge reads one contiguous 512B region (K at +0, V at +128 elems).
//   Head score = 1 xor-1 shuffle. Final cross-quarter combine: xor-16/32.
//   Buckets padded: beg = w<<6, end = beg + counts[w].
//   attn may alias q (row w read at start / written at end by wave w only).
// ---------------------------------------------------------------------------
__global__ __launch_bounds__(256)
void agg_kernel(const unsigned short* qv, const unsigned short* __restrict__ kvv,
                const int* __restrict__ counts, const int* __restrict__ eslot,
                unsigned short* attn, int n_nodes)
{
    int w    = (int)((blockIdx.x * 256 + threadIdx.x) >> 6);
    int lane = threadIdx.x & 63;
    if (w >= n_nodes) return;
    const int g  = lane >> 4;   // edge slot within iteration
    const int li = lane & 15;   // 8-dim chunk; head = li>>1

    // q chunk: dims 8*li .. 8*li+7 (quarters redundantly load same 256B row -> L1)
    float qf[8];
    {
        uint4 qb = *(const uint4*)(qv + (size_t)w * 128 + li * 8);
        const unsigned* qp = (const unsigned*)&qb;
#pragma unroll
        for (int j = 0; j < 4; ++j) {
            qf[2 * j]     = bf2f((unsigned short)(qp[j] & 0xffff));
            qf[2 * j + 1] = bf2f((unsigned short)(qp[j] >> 16));
        }
    }

    const int beg = w << CAPLOG;
    const int end = beg + counts[w];
    float acc[8] = {0.f, 0.f, 0.f, 0.f, 0.f, 0.f, 0.f, 0.f};
    float z = 0.f;

    for (int e = beg; e < end; e += 8) {
        int  i0 = e + g;
        int  i1 = e + g + 4;
        bool v0 = i0 < end;
        bool v1 = i1 < end;
        int  s0 = eslot[v0 ? i0 : beg];
        int  s1 = eslot[v1 ? i1 : beg];

        const unsigned short* b0 = kvv + (size_t)s0 * 256 + li * 8;
        const unsigned short* b1 = kvv + (size_t)s1 * 256 + li * 8;
        uint4 kb0 = *(const uint4*)(b0);
        uint4 vb0 = *(const uint4*)(b0 + 128);
        uint4 kb1 = *(const uint4*)(b1);
        uint4 vb1 = *(const uint4*)(b1 + 128);

        const unsigned* kp0 = (const unsigned*)&kb0;
        const unsigned* kp1 = (const unsigned*)&kb1;
        float p0 = 0.f, p1 = 0.f;
#pragma unroll
        for (int j = 0; j < 4; ++j) {
            p0 = fmaf(bf2f((unsigned short)(kp0[j] & 0xffff)), qf[2 * j],     p0);
            p0 = fmaf(bf2f((unsigned short)(kp0[j] >> 16)),    qf[2 * j + 1], p0);
            p1 = fmaf(bf2f((unsigned short)(kp1[j] & 0xffff)), qf[2 * j],     p1);
            p1 = fmaf(bf2f((unsigned short)(kp1[j] >> 16)),    qf[2 * j + 1], p1);
        }
        p0 += __shfl_xor(p0, 1, 64);   // full 16-dim head score
        p1 += __shfl_xor(p1, 1, 64);

        float sv0 = __expf(fminf(fmaxf(p0 * 0.25f, -5.f), 5.f));
        float sv1 = __expf(fminf(fmaxf(p1 * 0.25f, -5.f), 5.f));
        sv0 = v0 ? sv0 : 0.f;
        sv1 = v1 ? sv1 : 0.f;

        const unsigned* vp0 = (const unsigned*)&vb0;
        const unsigned* vp1 = (const unsigned*)&vb1;
#pragma unroll
        for (int j = 0; j < 4; ++j) {
            acc[2 * j]     = fmaf(sv0, bf2f((unsigned short)(vp0[j] & 0xffff)), acc[2 * j]);
            acc[2 * j + 1] = fmaf(sv0, bf2f((unsigned short)(vp0[j] >> 16)),    acc[2 * j + 1]);
            acc[2 * j]     = fmaf(sv1, bf2f((unsigned short)(vp1[j] & 0xffff)), acc[2 * j]);
            acc[2 * j + 1] = fmaf(sv1, bf2f((unsigned short)(vp1[j] >> 16)),    acc[2 * j + 1]);
        }
        z += sv0 + sv1;
    }

    // combine the 4 edge-slot quarters (each lane group holds same dims/head)
#pragma unroll
    for (int o = 16; o < 64; o <<= 1) {
#pragma unroll
        for (int j = 0; j < 8; ++j) acc[j] += __shfl_xor(acc[j], o, 64);
        z += __shfl_xor(z, o, 64);
    }

    if (g == 0) {
        float inv = 1.f / (z + 1e-6f);
        unsigned ow[4];
#pragma unroll
        for (int j = 0; j < 4; ++j)
            ow[j] = (unsigned)f2bf(acc[2 * j] * inv) |
                    ((unsigned)f2bf(acc[2 * j + 1] * inv) << 16);
        *(uint4*)(attn + (size_t)w * 128 + li * 8) = *(const uint4*)ow;
    }
}

// ---------------------------------------------------------------------------
extern "C" void kernel_launch(void* const* d_in, const int* in_sizes, int n_in,
                              void* d_out, int out_size, void* d_ws, size_t ws_size,
                              hipStream_t stream)
{
    const float* h_in  = (const float*)d_in[0];
    const int*   src   = (const int*)d_in[1];
    const int*   dst   = (const int*)d_in[2];
    const float* W_emb = (const float*)d_in[3];
    const float* Wq    = (const float*)d_in[4];
    const float* bq    = (const float*)d_in[5];
    const float* Wk    = (const float*)d_in[6];
    const float* bk    = (const float*)d_in[7];
    const float* Wv    = (const float*)d_in[8];
    const float* bv    = (const float*)d_in[9];
    const float* Wo    = (const float*)d_in[10];
    const float* bo    = (const float*)d_in[11];
    const float* ln1w  = (const float*)d_in[12];
    const float* ln1b  = (const float*)d_in[13];
    const float* Wf1   = (const float*)d_in[14];
    const float* bf1   = (const float*)d_in[15];
    const float* Wf2   = (const float*)d_in[16];
    const float* bf2   = (const float*)d_in[17];
    const float* ln2w  = (const float*)d_in[18];
    const float* ln2b  = (const float*)d_in[19];
    float* out = (float*)d_out;

    const int N = N_NODES, E = N_EDGES;
    const size_t NF = (size_t)N * DMODEL;

    float*          hbuf  = (float*)d_ws;
    unsigned short* hbf   = (unsigned short*)(hbuf + NF);
    unsigned short* qbuf  = hbf + NF;
    unsigned short* kvbuf = qbuf + NF;        // [N][256]: K row | V row interleaved
    unsigned short* wf    = kvbuf + 2 * NF;
    int* counts = (int*)(wf + 278528);
    // padded edge buckets live in d_out: dead until layer-1's fused f2+LN2
    // (which completely overwrites it, after layer-1 agg consumed eslot).
    int* eslot  = (int*)d_out;
    unsigned short* fbuf = kvbuf;   // [N][256] bf16 FFN hidden (same footprint)

    const int EMB_O = 0, Q_O = 16384, K_O = 49152, V_O = 81920, O_O = 114688,
              F1_O = 147456, F2_O = 212992;

    const int rowBlocks = (N + 3) / 4;
    const int GX = 391;   // 2 m-tiles/wave: measured-best B-amortization point (R7)

    // ---- counts zero (scatter halves are fused into emb/qkv dispatches) ----
    hipMemsetAsync(counts, 0, (size_t)N * sizeof(int), stream);

    // ---- weight prep ----
    PrepArgs pa;
    pa.seg[0]  = {W_emb,          128, 128, EMB_O};
    pa.seg[1]  = {Wq,             128, 128, Q_O};
    pa.seg[2]  = {Wq + 16384,     128, 128, Q_O + 16384};
    pa.seg[3]  = {Wk,             128, 128, K_O};
    pa.seg[4]  = {Wk + 16384,     128, 128, K_O + 16384};
    pa.seg[5]  = {Wv,             128, 128, V_O};
    pa.seg[6]  = {Wv + 16384,     128, 128, V_O + 16384};
    pa.seg[7]  = {Wo,             128, 128, O_O};
    pa.seg[8]  = {Wo + 16384,     128, 128, O_O + 16384};
    pa.seg[9]  = {Wf1,            128, 256, F1_O};
    pa.seg[10] = {Wf1 + 32768,    128, 256, F1_O + 32768};
    pa.seg[11] = {Wf2,            256, 128, F2_O};
    pa.seg[12] = {Wf2 + 32768,    256, 128, F2_O + 32768};
    prep_kernel<<<dim3(128, 13), 256, 0, stream>>>(pa, wf);

    // ---- embedding GEMM + scatter half 1 (edges [0, ESPLIT)) ----
    emb_sc_gemm<<<dim3(GX, 2), 256, 0, stream>>>(
        h_in, wf + EMB_O, hbuf, hbf, MTILES, src, dst, counts, eslot, 0, ESPLIT);

    for (int l = 0; l < 2; ++l) {
        // Q,K,V in one dispatch (+ scatter half 2 on layer 0)
        QkvPtrs qp;
        qp.bias[0] = bq + l * 128; qp.bias[1] = bk + l * 128; qp.bias[2] = bv + l * 128;
        qp.out[0] = qbuf;   qp.ldc[0] = 128;
        qp.out[1] = kvbuf;  qp.ldc[1] = 256;
        qp.out[2] = kvbuf + 128; qp.ldc[2] = 256;
        qkv_sc_gemm<<<dim3(GX, l == 0 ? 4 : 3), 256, 0, stream>>>(
            hbf, wf + Q_O + l * 16384, qp, MTILES, src, dst, counts, eslot,
            l == 0 ? ESPLIT : 0, l == 0 ? E : 0);

        // attention aggregate (attn aliases qbuf)
        agg_kernel<<<rowBlocks, 256, 0, stream>>>(qbuf, kvbuf, counts, eslot, qbuf, N);

        // hx = LN1(h + attn @ Wo + bo)  [fused GEMM+residual+LN] -> hbuf + hbf
        mfma_gemm<4, 8, 3, false, true, true><<<dim3(GX, 1), 256, 0, stream>>>(
            qbuf, wf + O_O + l * 16384, bo + l * 128, hbuf, hbuf, hbf,
            ln1w + l * 128, ln1b + l * 128, 128, 128, MTILES);

        // f1 = relu(hx @ Wf1 + bf1) -> bf16 [N,256]
        mfma_gemm<4, 8, 1, false, false, true><<<dim3(GX, 2), 256, 0, stream>>>(
            hbf, wf + F1_O + l * 32768, bf1 + l * 256, nullptr, nullptr, fbuf,
            nullptr, nullptr, 128, 256, MTILES);

        // h = LN2(hx + f1 @ Wf2 + bf2)  [fused GEMM+residual+LN, full 128-col
        // rows per block via NT=8; B read per-use from 64KB LDS panel]
        if (l == 0)
            mfma_gemm<8, 8, 3, false, true, true><<<dim3(GX, 1), 256, 0, stream>>>(
                fbuf, wf + F2_O, bf2, hbuf, hbuf, hbf,
                ln2w, ln2b, 256, 128, MTILES);
        else
            mfma_gemm<8, 8, 3, false, true, false><<<dim3(GX, 1), 256, 0, stream>>>(
                fbuf, wf + F2_O + 32768, bf2 + 128, hbuf, out, nullptr,
                ln2w + 128, ln2b + 128, 256, 128, MTILES);
    }
}

// Round 11
// 450.644 us; speedup vs baseline: 1.0120x; 1.0120x over previous
//
#include <hip/hip_runtime.h>
#include <math.h>

static constexpr int N_NODES = 50000;
static constexpr int N_EDGES = 800000;
static constexpr int DMODEL  = 128;
static constexpr int MTILES  = N_NODES / 16;   // 3125 exactly
static constexpr int CAPLOG  = 6;              // 64 slots/node; max degree ~40 (Poisson(16))
static constexpr int ESPLIT  = 400384;         // scatter split point

typedef __attribute__((ext_vector_type(8))) short short8;   // 8 bf16 (4 VGPRs)
typedef __attribute__((ext_vector_type(4))) float float4v;  // 4 fp32 acc

__device__ __forceinline__ unsigned short f2bf(float f) {
    unsigned u = __builtin_bit_cast(unsigned, f);
    u += 0x7fffu + ((u >> 16) & 1u);
    return (unsigned short)(u >> 16);
}
__device__ __forceinline__ float bf2f(unsigned short b) {
    unsigned u = ((unsigned)b) << 16;
    return __builtin_bit_cast(float, u);
}

// ---------------------------------------------------------------------------
// Weight prep: fp32 [K][N] row-major -> bf16 MFMA B-fragment order.
//   idx = (nt*ksteps + s)*512 + quad*128 + c*8 + j   (nt=n>>4, c=n&15, s=k>>5)
// ---------------------------------------------------------------------------
struct PrepSeg { const float* src; int K; int N; int dstOff; };
struct PrepArgs { PrepSeg seg[13]; };

__global__ void prep_kernel(PrepArgs pa, unsigned short* wf)
{
    PrepSeg sg = pa.seg[blockIdx.y];
    int e = blockIdx.x * 256 + threadIdx.x;
    int total = sg.K * sg.N;
    if (e >= total) return;
    int n = e % sg.N;
    int k = e / sg.N;
    int ks = sg.K >> 5;
    int nt = n >> 4, c = n & 15, s = k >> 5, q = (k >> 3) & 3, jj = k & 7;
    int di = sg.dstOff + (nt * ks + s) * 512 + q * 128 + c * 8 + jj;
    wf[di] = f2bf(sg.src[e]);
}

// ---------------------------------------------------------------------------
// Padded one-pass bucket build body: rank = atomicAdd(counts[dst]), slot into
// eslot[dst*64 + rank]. Fused into GEMM dispatches (extra blockIdx.y
// partition). Blocks whose whole range is past eend exit immediately
// (grid may be larger than the edge range).
// ---------------------------------------------------------------------------
__device__ __forceinline__ void scatter_body(
    const int* __restrict__ src, const int* __restrict__ dst,
    int* counts, int* eslot, int ebeg, int eend)
{
    int blk = ebeg + blockIdx.x * 1024;
    if (blk >= eend) return;
    int base = blk + threadIdx.x;
    int d[4], s[4];
    bool v[4];
#pragma unroll
    for (int k = 0; k < 4; ++k) {
        int e = base + k * 256;
        v[k] = e < eend;
        int ec = v[k] ? e : ebeg;
        d[k] = dst[ec];
        s[k] = src[ec];
    }
#pragma unroll
    for (int k = 0; k < 4; ++k) {
        if (v[k]) {
            int r = atomicAdd(&counts[d[k]], 1);
            eslot[(d[k] << CAPLOG) + r] = s[k];
        }
    }
}

// ---------------------------------------------------------------------------
// MFMA GEMM body with LDS-staged B (R8 win: B-reload from L2 was the
// first-order cost; per-block staging cuts it to ~12.5MB/dispatch). With
// staging in place, grid can be sized for TLP (GX=782: 1 m-tile/wave,
// ~12 waves/CU) without the R7 B-traffic blowup.
// EPI: 0=bias, 1=bias+relu, 2=bias+residual, 3=bias+residual+LayerNorm
// (EPI 3 requires NT*16==128, colBase==0).
// ---------------------------------------------------------------------------
template<int KSTEPS, int NT, int EPI, bool AF32, bool WRF, bool WRB>
__device__ __forceinline__ void gemm_body(
    const void* __restrict__ Ap, const unsigned short* __restrict__ Wfc,
    const float* __restrict__ bias, const float* res,
    float* Cf, unsigned short* Cb,
    const float* __restrict__ lnw, const float* __restrict__ lnb,
    int ldA, int ldC, int mtiles, int colBase)
{
    const int lane = threadIdx.x & 63;
    const int c = lane & 15;
    const int q = lane >> 4;

    // ---- cooperative B-panel stage ----
    __shared__ unsigned short smB[NT * KSTEPS * 512];
    {
        const int totalVec = NT * KSTEPS * 64;   // uint4 count
        const uint4* gsrc = (const uint4*)Wfc;
        uint4* sdst = (uint4*)smB;
#pragma unroll
        for (int i = threadIdx.x; i < totalVec; i += 256)
            sdst[i] = gsrc[i];
    }
    __syncthreads();

    short8 bfrag[NT][KSTEPS];
#pragma unroll
    for (int nt = 0; nt < NT; ++nt)
#pragma unroll
        for (int s = 0; s < KSTEPS; ++s)
            bfrag[nt][s] = *(const short8*)(smB + (nt * KSTEPS + s) * 512 + lane * 8);

    float bb[NT];
#pragma unroll
    for (int nt = 0; nt < NT; ++nt)
        bb[nt] = bias ? bias[colBase + nt * 16 + c] : 0.f;

    float lw[NT], lb[NT];
    if (EPI == 3) {
#pragma unroll
        for (int nt = 0; nt < NT; ++nt) {
            lw[nt] = lnw[nt * 16 + c];
            lb[nt] = lnb[nt * 16 + c];
        }
    }

    const int wid = blockIdx.x * 4 + (threadIdx.x >> 6);
    const int nw  = gridDim.x * 4;

    for (int mt = wid; mt < mtiles; mt += nw) {
        const int row0 = mt * 16;
        short8 afrag[KSTEPS];
        if (AF32) {
            const float* A32 = (const float*)Ap;
#pragma unroll
            for (int s = 0; s < KSTEPS; ++s) {
                const float4* p = (const float4*)(A32 + (size_t)(row0 + c) * ldA + s * 32 + q * 8);
                float4 x0 = p[0], x1 = p[1];
                short8 a;
                a[0] = (short)f2bf(x0.x); a[1] = (short)f2bf(x0.y);
                a[2] = (short)f2bf(x0.z); a[3] = (short)f2bf(x0.w);
                a[4] = (short)f2bf(x1.x); a[5] = (short)f2bf(x1.y);
                a[6] = (short)f2bf(x1.z); a[7] = (short)f2bf(x1.w);
                afrag[s] = a;
            }
        } else {
            const unsigned short* Ab = (const unsigned short*)Ap;
#pragma unroll
            for (int s = 0; s < KSTEPS; ++s)
                afrag[s] = *(const short8*)(Ab + (size_t)(row0 + c) * ldA + s * 32 + q * 8);
        }

        float4v acc[NT];
#pragma unroll
        for (int nt = 0; nt < NT; ++nt) acc[nt] = (float4v)0.f;
#pragma unroll
        for (int s = 0; s < KSTEPS; ++s)
#pragma unroll
            for (int nt = 0; nt < NT; ++nt)
                acc[nt] = __builtin_amdgcn_mfma_f32_16x16x32_bf16(afrag[s], bfrag[nt][s], acc[nt], 0, 0, 0);

        // epilogue: C row = row0 + q*4 + r, col = colBase + nt*16 + c
#pragma unroll
        for (int nt = 0; nt < NT; ++nt) {
            const int col = colBase + nt * 16 + c;
#pragma unroll
            for (int r = 0; r < 4; ++r) {
                const int grow = row0 + q * 4 + r;
                float v = acc[nt][r] + bb[nt];
                if (EPI == 2 || EPI == 3) v += res[(size_t)grow * ldC + col];
                if (EPI == 1) v = fmaxf(v, 0.f);
                acc[nt][r] = v;
            }
        }

        if (EPI == 3) {
            // full-row LayerNorm: reduce over 16 lanes of quad (cols) x NT regs
#pragma unroll
            for (int r = 0; r < 4; ++r) {
                float s = 0.f, ss = 0.f;
#pragma unroll
                for (int nt = 0; nt < NT; ++nt) {
                    float v = acc[nt][r];
                    s += v; ss = fmaf(v, v, ss);
                }
#pragma unroll
                for (int o = 1; o < 16; o <<= 1) {
                    s  += __shfl_xor(s, o, 64);
                    ss += __shfl_xor(ss, o, 64);
                }
                float m   = s * (1.0f / 128.0f);
                float var = ss * (1.0f / 128.0f) - m * m;
                float rs  = rsqrtf(var + 1e-5f);
                const int grow = row0 + q * 4 + r;
#pragma unroll
                for (int nt = 0; nt < NT; ++nt) {
                    float v = (acc[nt][r] - m) * rs * lw[nt] + lb[nt];
                    if (WRF) Cf[(size_t)grow * ldC + nt * 16 + c] = v;
                    if (WRB) Cb[(size_t)grow * ldC + nt * 16 + c] = f2bf(v);
                }
            }
        } else {
#pragma unroll
            for (int nt = 0; nt < NT; ++nt) {
                const int col = colBase + nt * 16 + c;
#pragma unroll
                for (int r = 0; r < 4; ++r) {
                    const int grow = row0 + q * 4 + r;
                    if (WRF) Cf[(size_t)grow * ldC + col] = acc[nt][r];
                    if (WRB) Cb[(size_t)grow * ldC + col] = f2bf(acc[nt][r]);
                }
            }
        }
    }
}

template<int KSTEPS, int NT, int EPI, bool AF32, bool WRF, bool WRB>
__global__ __launch_bounds__(256, 2)
void mfma_gemm(const void* __restrict__ Ap, const unsigned short* __restrict__ Wf,
               const float* __restrict__ bias, const float* res,
               float* Cf, unsigned short* Cb,
               const float* __restrict__ lnw, const float* __restrict__ lnb,
               int ldA, int ldC, int mtiles)
{
    const int colBase = blockIdx.y * NT * 16;
    const unsigned short* Wfc = Wf + (size_t)blockIdx.y * NT * KSTEPS * 512;
    gemm_body<KSTEPS, NT, EPI, AF32, WRF, WRB>(
        Ap, Wfc, bias, res, Cf, Cb, lnw, lnb, ldA, ldC, mtiles, colBase);
}

// Embedding GEMM fused with scatter half 1 (blockIdx.y==1 -> scatter).
__global__ __launch_bounds__(256, 2)
void emb_sc_gemm(const float* __restrict__ A, const unsigned short* __restrict__ Wf,
                 float* Cf, unsigned short* Cb, int mtiles,
                 const int* __restrict__ src, const int* __restrict__ dst,
                 int* counts, int* eslot, int ebeg, int eend)
{
    if (blockIdx.y == 1) {
        scatter_body(src, dst, counts, eslot, ebeg, eend);
        return;
    }
    gemm_body<4, 8, 0, true, true, true>(
        A, Wf, nullptr, nullptr, Cf, Cb, nullptr, nullptr, 128, 128, mtiles, 0);
}

// Q/K/V fused + scatter half 2 (blockIdx.y==3 -> scatter on layer 0).
// K and V write into the interleaved kv buffer [node][K 0..127 | V 128..255].
struct QkvPtrs { const float* bias[3]; unsigned short* out[3]; int ldc[3]; };

__global__ __launch_bounds__(256, 2)
void qkv_sc_gemm(const unsigned short* __restrict__ A, const unsigned short* __restrict__ WfBase,
                 QkvPtrs ptrs, int mtiles,
                 const int* __restrict__ src, const int* __restrict__ dst,
                 int* counts, int* eslot, int ebeg, int eend)
{
    if (blockIdx.y == 3) {
        scatter_body(src, dst, counts, eslot, ebeg, eend);
        return;
    }
    const int sel = blockIdx.y;
    gemm_body<4, 8, 0, false, false, true>(
        A, WfBase + (size_t)sel * 32768, ptrs.bias[sel], nullptr,
        nullptr, ptrs.out[sel], nullptr, nullptr, 128, ptrs.ldc[sel], mtiles, 0);
}

// ---------------------------------------------------------------------------
// LayerNorm rows of [M,128] fp32; writes fp32 (+optional bf16 mirror).
// ---------------------------------------------------------------------------
__global__ __launch_bounds__(256)
void ln_kernel(const float* x, const float* __restrict__ w,
               const float* __restrict__ b, float* outf, unsigned short* outb, int M)
{
    int row  = (int)((blockIdx.x * 256 + threadIdx.x) >> 6);
    int lane = threadIdx.x & 63;
    if (row >= M) return;
    const float* xr = x + (size_t)row * 128;
    float x0 = xr[lane];
    float x1 = xr[lane + 64];
    float s  = x0 + x1;
    float ss = x0 * x0 + x1 * x1;
#pragma unroll
    for (int o = 1; o < 64; o <<= 1) {
        s  += __shfl_xor(s, o, 64);
        ss += __shfl_xor(ss, o, 64);
    }
    float m   = s * (1.0f / 128.0f);
    float var = ss * (1.0f / 128.0f) - m * m;
    float rs  = rsqrtf(var + 1e-5f);
    float o0 = (x0 - m) * rs * w[lane] + b[lane];
    float o1 = (x1 - m) * rs * w[lane + 64] + b[lane + 64];
    outf[(size_t)row * 128 + lane]      = o0;
    outf[(size_t)row * 128 + lane + 64] = o1;
    if (outb) {
        outb[(size_t)row * 128 + lane]      = f2bf(o0);
        outb[(size_t)row * 128 + lane + 64] = f2bf(o1);
    }
}

// ---------------------------------------------------------------------------
// Attention aggregation (R4 form — measured best: 55.7us, VGPR 32, occ 67%).
// 16-lanes-per-edge, 8 edges/iter. TLP at ~8 waves/SIMD hides gather latency;
// deeper per-wave unroll/prefetch measured WORSE (R2: 16-edge, R5: dbuf).
//   wave = one dst node; quarter g=lane>>4 owns edge slots g and g+4; lane
//   li=lane&15 covers dims 8*li..8*li+7 (head = li>>1). K|V interleaved rows:
//   each edge reads one contiguous 512B region (K at +0, V at +128 elems).
//   Head score = 1 xor-1 shuffle. Final cross-quarter combine: xor-16/32.
//   Buckets padded: beg = w<<6, end = beg + counts[w].
//   attn may alias q (row w read at start / written at end by wave w only).
// ---------------------------------------------------------------------------
__global__ __launch_bounds__(256)
void agg_kernel(const unsigned short* qv, const unsigned short* __restrict__ kvv,
                const int* __restrict__ counts, const int* __restrict__ eslot,
                unsigned short* attn, int n_nodes)
{
    int w    = (int)((blockIdx.x * 256 + threadIdx.x) >> 6);
    int lane = threadIdx.x & 63;
    if (w >= n_nodes) return;
    const int g  = lane >> 4;   // edge slot within iteration
    const int li = lane & 15;   // 8-dim chunk; head = li>>1

    // q chunk: dims 8*li .. 8*li+7 (quarters redundantly load same 256B row -> L1)
    float qf[8];
    {
        uint4 qb = *(const uint4*)(qv + (size_t)w * 128 + li * 8);
        const unsigned* qp = (const unsigned*)&qb;
#pragma unroll
        for (int j = 0; j < 4; ++j) {
            qf[2 * j]     = bf2f((unsigned short)(qp[j] & 0xffff));
            qf[2 * j + 1] = bf2f((unsigned short)(qp[j] >> 16));
        }
    }

    const int beg = w << CAPLOG;
    const int end = beg + counts[w];
    float acc[8] = {0.f, 0.f, 0.f, 0.f, 0.f, 0.f, 0.f, 0.f};
    float z = 0.f;

    for (int e = beg; e < end; e += 8) {
        int  i0 = e + g;
        int  i1 = e + g + 4;
        bool v0 = i0 < end;
        bool v1 = i1 < end;
        int  s0 = eslot[v0 ? i0 : beg];
        int  s1 = eslot[v1 ? i1 : beg];

        const unsigned short* b0 = kvv + (size_t)s0 * 256 + li * 8;
        const unsigned short* b1 = kvv + (size_t)s1 * 256 + li * 8;
        uint4 kb0 = *(const uint4*)(b0);
        uint4 vb0 = *(const uint4*)(b0 + 128);
        uint4 kb1 = *(const uint4*)(b1);
        uint4 vb1 = *(const uint4*)(b1 + 128);

        const unsigned* kp0 = (const unsigned*)&kb0;
        const unsigned* kp1 = (const unsigned*)&kb1;
        float p0 = 0.f, p1 = 0.f;
#pragma unroll
        for (int j = 0; j < 4; ++j) {
            p0 = fmaf(bf2f((unsigned short)(kp0[j] & 0xffff)), qf[2 * j],     p0);
            p0 = fmaf(bf2f((unsigned short)(kp0[j] >> 16)),    qf[2 * j + 1], p0);
            p1 = fmaf(bf2f((unsigned short)(kp1[j] & 0xffff)), qf[2 * j],     p1);
            p1 = fmaf(bf2f((unsigned short)(kp1[j] >> 16)),    qf[2 * j + 1], p1);
        }
        p0 += __shfl_xor(p0, 1, 64);   // full 16-dim head score
        p1 += __shfl_xor(p1, 1, 64);

        float sv0 = __expf(fminf(fmaxf(p0 * 0.25f, -5.f), 5.f));
        float sv1 = __expf(fminf(fmaxf(p1 * 0.25f, -5.f), 5.f));
        sv0 = v0 ? sv0 : 0.f;
        sv1 = v1 ? sv1 : 0.f;

        const unsigned* vp0 = (const unsigned*)&vb0;
        const unsigned* vp1 = (const unsigned*)&vb1;
#pragma unroll
        for (int j = 0; j < 4; ++j) {
            acc[2 * j]     = fmaf(sv0, bf2f((unsigned short)(vp0[j] & 0xffff)), acc[2 * j]);
            acc[2 * j + 1] = fmaf(sv0, bf2f((unsigned short)(vp0[j] >> 16)),    acc[2 * j + 1]);
            acc[2 * j]     = fmaf(sv1, bf2f((unsigned short)(vp1[j] & 0xffff)), acc[2 * j]);
            acc[2 * j + 1] = fmaf(sv1, bf2f((unsigned short)(vp1[j] >> 16)),    acc[2 * j + 1]);
        }
        z += sv0 + sv1;
    }

    // combine the 4 edge-slot quarters (each lane group holds same dims/head)
#pragma unroll
    for (int o = 16; o < 64; o <<= 1) {
#pragma unroll
        for (int j = 0; j < 8; ++j) acc[j] += __shfl_xor(acc[j], o, 64);
        z += __shfl_xor(z, o, 64);
    }

    if (g == 0) {
        float inv = 1.f / (z + 1e-6f);
        unsigned ow[4];
#pragma unroll
        for (int j = 0; j < 4; ++j)
            ow[j] = (unsigned)f2bf(acc[2 * j] * inv) |
                    ((unsigned)f2bf(acc[2 * j + 1] * inv) << 16);
        *(uint4*)(attn + (size_t)w * 128 + li * 8) = *(const uint4*)ow;
    }
}

// ---------------------------------------------------------------------------
extern "C" void kernel_launch(void* const* d_in, const int* in_sizes, int n_in,
                              void* d_out, int out_size, void* d_ws, size_t ws_size,
                              hipStream_t stream)
{
    const float* h_in  = (const float*)d_in[0];
    const int*   src   = (const int*)d_in[1];
    const int*   dst   = (const int*)d_in[2];
    const float* W_emb = (const float*)d_in[3];
    const float* Wq    = (const float*)d_in[4];
    const float* bq    = (const float*)d_in[5];
    const float* Wk    = (const float*)d_in[6];
    const float* bk    = (const float*)d_in[7];
    const float* Wv    = (const float*)d_in[8];
    const float* bv    = (const float*)d_in[9];
    const float* Wo    = (const float*)d_in[10];
    const float* bo    = (const float*)d_in[11];
    const float* ln1w  = (const float*)d_in[12];
    const float* ln1b  = (const float*)d_in[13];
    const float* Wf1   = (const float*)d_in[14];
    const float* bf1   = (const float*)d_in[15];
    const float* Wf2   = (const float*)d_in[16];
    const float* bf2   = (const float*)d_in[17];
    const float* ln2w  = (const float*)d_in[18];
    const float* ln2b  = (const float*)d_in[19];
    float* out = (float*)d_out;

    const int N = N_NODES, E = N_EDGES;
    const size_t NF = (size_t)N * DMODEL;

    float*          hbuf  = (float*)d_ws;
    unsigned short* hbf   = (unsigned short*)(hbuf + NF);
    unsigned short* qbuf  = hbf + NF;
    unsigned short* kvbuf = qbuf + NF;        // [N][256]: K row | V row interleaved
    unsigned short* wf    = kvbuf + 2 * NF;
    int* counts = (int*)(wf + 278528);
    // padded edge buckets live in d_out: dead until the final ln_kernel
    // (which completely overwrites it). 50K * 64 slots * 4B = 12.8 MB < 25.6 MB.
    int* eslot  = (int*)d_out;
    unsigned short* fbuf = kvbuf;   // [N][256] bf16 FFN hidden (same footprint)

    const int EMB_O = 0, Q_O = 16384, K_O = 49152, V_O = 81920, O_O = 114688,
              F1_O = 147456, F2_O = 212992;

    const int rowBlocks = (N + 3) / 4;
    const int GX = 782;   // 1 m-tile/wave; TLP-sized now that LDS staging
                          // removed the R7 per-wave B-reload penalty

    // ---- counts zero (scatter halves are fused into emb/qkv dispatches) ----
    hipMemsetAsync(counts, 0, (size_t)N * sizeof(int), stream);

    // ---- weight prep ----
    PrepArgs pa;
    pa.seg[0]  = {W_emb,          128, 128, EMB_O};
    pa.seg[1]  = {Wq,             128, 128, Q_O};
    pa.seg[2]  = {Wq + 16384,     128, 128, Q_O + 16384};
    pa.seg[3]  = {Wk,             128, 128, K_O};
    pa.seg[4]  = {Wk + 16384,     128, 128, K_O + 16384};
    pa.seg[5]  = {Wv,             128, 128, V_O};
    pa.seg[6]  = {Wv + 16384,     128, 128, V_O + 16384};
    pa.seg[7]  = {Wo,             128, 128, O_O};
    pa.seg[8]  = {Wo + 16384,     128, 128, O_O + 16384};
    pa.seg[9]  = {Wf1,            128, 256, F1_O};
    pa.seg[10] = {Wf1 + 32768,    128, 256, F1_O + 32768};
    pa.seg[11] = {Wf2,            256, 128, F2_O};
    pa.seg[12] = {Wf2 + 32768,    256, 128, F2_O + 32768};
    prep_kernel<<<dim3(128, 13), 256, 0, stream>>>(pa, wf);

    // ---- embedding GEMM + scatter half 1 (edges [0, ESPLIT)) ----
    emb_sc_gemm<<<dim3(GX, 2), 256, 0, stream>>>(
        h_in, wf + EMB_O, hbuf, hbf, MTILES, src, dst, counts, eslot, 0, ESPLIT);

    for (int l = 0; l < 2; ++l) {
        // Q,K,V in one dispatch (+ scatter half 2 on layer 0)
        QkvPtrs qp;
        qp.bias[0] = bq + l * 128; qp.bias[1] = bk + l * 128; qp.bias[2] = bv + l * 128;
        qp.out[0] = qbuf;   qp.ldc[0] = 128;
        qp.out[1] = kvbuf;  qp.ldc[1] = 256;
        qp.out[2] = kvbuf + 128; qp.ldc[2] = 256;
        qkv_sc_gemm<<<dim3(GX, l == 0 ? 4 : 3), 256, 0, stream>>>(
            hbf, wf + Q_O + l * 16384, qp, MTILES, src, dst, counts, eslot,
            l == 0 ? ESPLIT : 0, l == 0 ? E : 0);

        // attention aggregate (attn aliases qbuf)
        agg_kernel<<<rowBlocks, 256, 0, stream>>>(qbuf, kvbuf, counts, eslot, qbuf, N);

        // hx = LN1(h + attn @ Wo + bo)  [fused GEMM+residual+LN] -> hbuf + hbf
        mfma_gemm<4, 8, 3, false, true, true><<<dim3(GX, 1), 256, 0, stream>>>(
            qbuf, wf + O_O + l * 16384, bo + l * 128, hbuf, hbuf, hbf,
            ln1w + l * 128, ln1b + l * 128, 128, 128, MTILES);

        // f1 = relu(hx @ Wf1 + bf1) -> bf16 [N,256]
        mfma_gemm<4, 8, 1, false, false, true><<<dim3(GX, 2), 256, 0, stream>>>(
            hbf, wf + F1_O + l * 32768, bf1 + l * 256, nullptr, nullptr, fbuf,
            nullptr, nullptr, 128, 256, MTILES);
        // h = hx + f1 @ Wf2 + bf2 (fp32, in-place residual)
        mfma_gemm<8, 4, 2, false, true, false><<<dim3(GX, 2), 256, 0, stream>>>(
            fbuf, wf + F2_O + l * 32768, bf2 + l * 128, hbuf, hbuf, nullptr,
            nullptr, nullptr, 256, 128, MTILES);

        // LN2 -> hbuf+hbf (layer 0) or d_out fp32 (layer 1)
        if (l == 0)
            ln_kernel<<<rowBlocks, 256, 0, stream>>>(hbuf, ln2w, ln2b, hbuf, hbf, N);
        else
            ln_kernel<<<rowBlocks, 256, 0, stream>>>(hbuf, ln2w + 128, ln2b + 128, out, nullptr, N);
    }
}

// Round 12
// 409.571 us; speedup vs baseline: 1.1135x; 1.1003x over previous
//
#include <hip/hip_runtime.h>
#include <math.h>

static constexpr int N_NODES = 50000;
static constexpr int N_EDGES = 800000;
static constexpr int DMODEL  = 128;
static constexpr int MTILES  = N_NODES / 16;   // 3125 exactly
static constexpr int CAPLOG  = 6;              // 64 slots/node; max degree ~40 (Poisson(16))
static constexpr int ESPLIT  = 400384;         // scatter split point

typedef __attribute__((ext_vector_type(8))) short short8;   // 8 bf16 (4 VGPRs)
typedef __attribute__((ext_vector_type(4))) float float4v;  // 4 fp32 acc

__device__ __forceinline__ unsigned short f2bf(float f) {
    unsigned u = __builtin_bit_cast(unsigned, f);
    u += 0x7fffu + ((u >> 16) & 1u);
    return (unsigned short)(u >> 16);
}
__device__ __forceinline__ float bf2f(unsigned short b) {
    unsigned u = ((unsigned)b) << 16;
    return __builtin_bit_cast(float, u);
}

// ---------------------------------------------------------------------------
// Weight prep: fp32 [K][N] row-major -> bf16 MFMA B-fragment order.
//   idx = (nt*ksteps + s)*512 + quad*128 + c*8 + j   (nt=n>>4, c=n&15, s=k>>5)
// blockIdx.y==13 zeroes the counts array (replaces the memset dispatch).
// ---------------------------------------------------------------------------
struct PrepSeg { const float* src; int K; int N; int dstOff; };
struct PrepArgs { PrepSeg seg[13]; };

__global__ void prep_kernel(PrepArgs pa, unsigned short* wf, int* counts)
{
    if (blockIdx.y == 13) {
        for (int i = blockIdx.x * 256 + threadIdx.x; i < N_NODES; i += 128 * 256)
            counts[i] = 0;
        return;
    }
    PrepSeg sg = pa.seg[blockIdx.y];
    int e = blockIdx.x * 256 + threadIdx.x;
    int total = sg.K * sg.N;
    if (e >= total) return;
    int n = e % sg.N;
    int k = e / sg.N;
    int ks = sg.K >> 5;
    int nt = n >> 4, c = n & 15, s = k >> 5, q = (k >> 3) & 3, jj = k & 7;
    int di = sg.dstOff + (nt * ks + s) * 512 + q * 128 + c * 8 + jj;
    wf[di] = f2bf(sg.src[e]);
}

// ---------------------------------------------------------------------------
// Padded one-pass bucket build body: rank = atomicAdd(counts[dst]), slot into
// eslot[dst*64 + rank]. Fused into GEMM dispatches (extra blockIdx.y
// partition). Blocks whose whole range is past eend exit immediately.
// ---------------------------------------------------------------------------
__device__ __forceinline__ void scatter_body(
    const int* __restrict__ src, const int* __restrict__ dst,
    int* counts, int* eslot, int ebeg, int eend)
{
    int blk = ebeg + blockIdx.x * 1024;
    if (blk >= eend) return;
    int base = blk + threadIdx.x;
    int d[4], s[4];
    bool v[4];
#pragma unroll
    for (int k = 0; k < 4; ++k) {
        int e = base + k * 256;
        v[k] = e < eend;
        int ec = v[k] ? e : ebeg;
        d[k] = dst[ec];
        s[k] = src[ec];
    }
#pragma unroll
    for (int k = 0; k < 4; ++k) {
        if (v[k]) {
            int r = atomicAdd(&counts[d[k]], 1);
            eslot[(d[k] << CAPLOG) + r] = s[k];
        }
    }
}

// ---------------------------------------------------------------------------
// MFMA GEMM body with LDS-staged B (R8 win; GX=391 = 2 m-tiles/wave is the
// measured-best operating point — R7/R11 showed 1 tile/wave loses to
// per-block fixed costs regardless of B source).
// EPI: 0=bias, 1=bias+relu, 2=bias+residual, 3=bias+residual+LayerNorm
// (EPI 3 requires NT*16==128, colBase==0).
// ---------------------------------------------------------------------------
template<int KSTEPS, int NT, int EPI, bool AF32, bool WRF, bool WRB>
__device__ __forceinline__ void gemm_body(
    const void* __restrict__ Ap, const unsigned short* __restrict__ Wfc,
    const float* __restrict__ bias, const float* res,
    float* Cf, unsigned short* Cb,
    const float* __restrict__ lnw, const float* __restrict__ lnb,
    int ldA, int ldC, int mtiles, int colBase)
{
    const int lane = threadIdx.x & 63;
    const int c = lane & 15;
    const int q = lane >> 4;

    // ---- cooperative B-panel stage ----
    __shared__ unsigned short smB[NT * KSTEPS * 512];
    {
        const int totalVec = NT * KSTEPS * 64;   // uint4 count
        const uint4* gsrc = (const uint4*)Wfc;
        uint4* sdst = (uint4*)smB;
#pragma unroll
        for (int i = threadIdx.x; i < totalVec; i += 256)
            sdst[i] = gsrc[i];
    }
    __syncthreads();

    short8 bfrag[NT][KSTEPS];
#pragma unroll
    for (int nt = 0; nt < NT; ++nt)
#pragma unroll
        for (int s = 0; s < KSTEPS; ++s)
            bfrag[nt][s] = *(const short8*)(smB + (nt * KSTEPS + s) * 512 + lane * 8);

    float bb[NT];
#pragma unroll
    for (int nt = 0; nt < NT; ++nt)
        bb[nt] = bias ? bias[colBase + nt * 16 + c] : 0.f;

    float lw[NT], lb[NT];
    if (EPI == 3) {
#pragma unroll
        for (int nt = 0; nt < NT; ++nt) {
            lw[nt] = lnw[nt * 16 + c];
            lb[nt] = lnb[nt * 16 + c];
        }
    }

    const int wid = blockIdx.x * 4 + (threadIdx.x >> 6);
    const int nw  = gridDim.x * 4;

    for (int mt = wid; mt < mtiles; mt += nw) {
        const int row0 = mt * 16;
        short8 afrag[KSTEPS];
        if (AF32) {
            const float* A32 = (const float*)Ap;
#pragma unroll
            for (int s = 0; s < KSTEPS; ++s) {
                const float4* p = (const float4*)(A32 + (size_t)(row0 + c) * ldA + s * 32 + q * 8);
                float4 x0 = p[0], x1 = p[1];
                short8 a;
                a[0] = (short)f2bf(x0.x); a[1] = (short)f2bf(x0.y);
                a[2] = (short)f2bf(x0.z); a[3] = (short)f2bf(x0.w);
                a[4] = (short)f2bf(x1.x); a[5] = (short)f2bf(x1.y);
                a[6] = (short)f2bf(x1.z); a[7] = (short)f2bf(x1.w);
                afrag[s] = a;
            }
        } else {
            const unsigned short* Ab = (const unsigned short*)Ap;
#pragma unroll
            for (int s = 0; s < KSTEPS; ++s)
                afrag[s] = *(const short8*)(Ab + (size_t)(row0 + c) * ldA + s * 32 + q * 8);
        }

        float4v acc[NT];
#pragma unroll
        for (int nt = 0; nt < NT; ++nt) acc[nt] = (float4v)0.f;
#pragma unroll
        for (int s = 0; s < KSTEPS; ++s)
#pragma unroll
            for (int nt = 0; nt < NT; ++nt)
                acc[nt] = __builtin_amdgcn_mfma_f32_16x16x32_bf16(afrag[s], bfrag[nt][s], acc[nt], 0, 0, 0);

        // epilogue: C row = row0 + q*4 + r, col = colBase + nt*16 + c
#pragma unroll
        for (int nt = 0; nt < NT; ++nt) {
            const int col = colBase + nt * 16 + c;
#pragma unroll
            for (int r = 0; r < 4; ++r) {
                const int grow = row0 + q * 4 + r;
                float v = acc[nt][r] + bb[nt];
                if (EPI == 2 || EPI == 3) v += res[(size_t)grow * ldC + col];
                if (EPI == 1) v = fmaxf(v, 0.f);
                acc[nt][r] = v;
            }
        }

        if (EPI == 3) {
#pragma unroll
            for (int r = 0; r < 4; ++r) {
                float s = 0.f, ss = 0.f;
#pragma unroll
                for (int nt = 0; nt < NT; ++nt) {
                    float v = acc[nt][r];
                    s += v; ss = fmaf(v, v, ss);
                }
#pragma unroll
                for (int o = 1; o < 16; o <<= 1) {
                    s  += __shfl_xor(s, o, 64);
                    ss += __shfl_xor(ss, o, 64);
                }
                float m   = s * (1.0f / 128.0f);
                float var = ss * (1.0f / 128.0f) - m * m;
                float rs  = rsqrtf(var + 1e-5f);
                const int grow = row0 + q * 4 + r;
#pragma unroll
                for (int nt = 0; nt < NT; ++nt) {
                    float v = (acc[nt][r] - m) * rs * lw[nt] + lb[nt];
                    if (WRF) Cf[(size_t)grow * ldC + nt * 16 + c] = v;
                    if (WRB) Cb[(size_t)grow * ldC + nt * 16 + c] = f2bf(v);
                }
            }
        } else {
#pragma unroll
            for (int nt = 0; nt < NT; ++nt) {
                const int col = colBase + nt * 16 + c;
#pragma unroll
                for (int r = 0; r < 4; ++r) {
                    const int grow = row0 + q * 4 + r;
                    if (WRF) Cf[(size_t)grow * ldC + col] = acc[nt][r];
                    if (WRB) Cb[(size_t)grow * ldC + col] = f2bf(acc[nt][r]);
                }
            }
        }
    }
}

template<int KSTEPS, int NT, int EPI, bool AF32, bool WRF, bool WRB>
__global__ __launch_bounds__(256, 2)
void mfma_gemm(const void* __restrict__ Ap, const unsigned short* __restrict__ Wf,
               const float* __restrict__ bias, const float* res,
               float* Cf, unsigned short* Cb,
               const float* __restrict__ lnw, const float* __restrict__ lnb,
               int ldA, int ldC, int mtiles)
{
    const int colBase = blockIdx.y * NT * 16;
    const unsigned short* Wfc = Wf + (size_t)blockIdx.y * NT * KSTEPS * 512;
    gemm_body<KSTEPS, NT, EPI, AF32, WRF, WRB>(
        Ap, Wfc, bias, res, Cf, Cb, lnw, lnb, ldA, ldC, mtiles, colBase);
}

// Embedding GEMM fused with scatter half 1 (blockIdx.y==1 -> scatter).
__global__ __launch_bounds__(256, 2)
void emb_sc_gemm(const float* __restrict__ A, const unsigned short* __restrict__ Wf,
                 float* Cf, unsigned short* Cb, int mtiles,
                 const int* __restrict__ src, const int* __restrict__ dst,
                 int* counts, int* eslot, int ebeg, int eend)
{
    if (blockIdx.y == 1) {
        scatter_body(src, dst, counts, eslot, ebeg, eend);
        return;
    }
    gemm_body<4, 8, 0, true, true, true>(
        A, Wf, nullptr, nullptr, Cf, Cb, nullptr, nullptr, 128, 128, mtiles, 0);
}

// Q/K/V fused + scatter half 2 (blockIdx.y==3 -> scatter on layer 0).
// K and V write into the interleaved kv buffer [node][K 0..127 | V 128..255].
struct QkvPtrs { const float* bias[3]; unsigned short* out[3]; int ldc[3]; };

__global__ __launch_bounds__(256, 2)
void qkv_sc_gemm(const unsigned short* __restrict__ A, const unsigned short* __restrict__ WfBase,
                 QkvPtrs ptrs, int mtiles,
                 const int* __restrict__ src, const int* __restrict__ dst,
                 int* counts, int* eslot, int ebeg, int eend)
{
    if (blockIdx.y == 3) {
        scatter_body(src, dst, counts, eslot, ebeg, eend);
        return;
    }
    const int sel = blockIdx.y;
    gemm_body<4, 8, 0, false, false, true>(
        A, WfBase + (size_t)sel * 32768, ptrs.bias[sel], nullptr,
        nullptr, ptrs.out[sel], nullptr, nullptr, 128, ptrs.ldc[sel], mtiles, 0);
}

// ---------------------------------------------------------------------------
// Fused f2 + residual + LN2 (replaces f2 GEMM + ln_kernel). Wave-pair
// NT-split: each pair owns one m-tile; half 0 computes cols 0-63, half 1
// cols 64-127. B = 4nt x 8ks = 32 frags IN REGISTERS (no 64KB LDS panel, no
// per-use LDS B reads — the R9 failure modes). LN row sums: per-half
// partials exchanged via 512B LDS + 2 barriers/iter (uniform trip count
// across all blocks -> barrier-safe). WRB: also write bf16 mirror (layer 0).
// ---------------------------------------------------------------------------
template<bool WRB>
__global__ __launch_bounds__(256, 2)
void f2ln_kernel(const unsigned short* __restrict__ A,    // fbuf [N][256] bf16
                 const unsigned short* __restrict__ Wfc,  // Wf2 frags (ks=8)
                 const float* __restrict__ bias,
                 const float* __restrict__ res,           // hbuf fp32
                 float* Cf, unsigned short* Cb,
                 const float* __restrict__ lnw, const float* __restrict__ lnb,
                 int mtiles)
{
    const int lane  = threadIdx.x & 63;
    const int c     = lane & 15;
    const int q     = lane >> 4;
    const int wid   = threadIdx.x >> 6;     // 0..3
    const int pairL = wid >> 1;             // pair within block
    const int half  = wid & 1;              // col half
    const int colBase = half * 64;

    __shared__ float sred[2][16][2][2];     // [pair][row][half][s,ss]

    short8 bfrag[4][8];
#pragma unroll
    for (int nt = 0; nt < 4; ++nt)
#pragma unroll
        for (int s = 0; s < 8; ++s)
            bfrag[nt][s] = *(const short8*)(Wfc + (size_t)((half * 4 + nt) * 8 + s) * 512 + lane * 8);

    float bb[4], lw[4], lb[4];
#pragma unroll
    for (int nt = 0; nt < 4; ++nt) {
        int col = colBase + nt * 16 + c;
        bb[nt] = bias[col]; lw[nt] = lnw[col]; lb[nt] = lnb[col];
    }

    const int pairG  = blockIdx.x * 2 + pairL;
    const int npairs = gridDim.x * 2;
    const int iters  = (mtiles + npairs - 1) / npairs;

    for (int it = 0; it < iters; ++it) {
        const int mt = pairG + it * npairs;
        const bool active = mt < mtiles;
        const int row0 = (active ? mt : 0) * 16;

        short8 afrag[8];
#pragma unroll
        for (int s = 0; s < 8; ++s)
            afrag[s] = *(const short8*)(A + (size_t)(row0 + c) * 256 + s * 32 + q * 8);

        float4v acc[4];
#pragma unroll
        for (int nt = 0; nt < 4; ++nt) acc[nt] = (float4v)0.f;
#pragma unroll
        for (int s = 0; s < 8; ++s)
#pragma unroll
            for (int nt = 0; nt < 4; ++nt)
                acc[nt] = __builtin_amdgcn_mfma_f32_16x16x32_bf16(afrag[s], bfrag[nt][s], acc[nt], 0, 0, 0);

        // v = acc + bias + residual
        float vv[4][4];
#pragma unroll
        for (int nt = 0; nt < 4; ++nt)
#pragma unroll
            for (int r = 0; r < 4; ++r)
                vv[nt][r] = acc[nt][r] + bb[nt] +
                            res[(size_t)(row0 + q * 4 + r) * 128 + colBase + nt * 16 + c];

        // per-row partial (s,ss) over this wave's 64 cols -> LDS
#pragma unroll
        for (int r = 0; r < 4; ++r) {
            float s  = vv[0][r] + vv[1][r] + vv[2][r] + vv[3][r];
            float ss = fmaf(vv[0][r], vv[0][r],
                       fmaf(vv[1][r], vv[1][r],
                       fmaf(vv[2][r], vv[2][r], vv[3][r] * vv[3][r])));
#pragma unroll
            for (int o = 1; o < 16; o <<= 1) {
                s  += __shfl_xor(s, o, 64);
                ss += __shfl_xor(ss, o, 64);
            }
            if (c == 0) {
                sred[pairL][q * 4 + r][half][0] = s;
                sred[pairL][q * 4 + r][half][1] = ss;
            }
        }
        __syncthreads();

#pragma unroll
        for (int r = 0; r < 4; ++r) {
            const int rr = q * 4 + r;
            float S  = sred[pairL][rr][0][0] + sred[pairL][rr][1][0];
            float SS = sred[pairL][rr][0][1] + sred[pairL][rr][1][1];
            float m   = S * (1.0f / 128.0f);
            float var = SS * (1.0f / 128.0f) - m * m;
            float rs  = rsqrtf(var + 1e-5f);
            if (active) {
                const int grow = row0 + rr;
#pragma unroll
                for (int nt = 0; nt < 4; ++nt) {
                    const int col = colBase + nt * 16 + c;
                    float v = (vv[nt][r] - m) * rs * lw[nt] + lb[nt];
                    Cf[(size_t)grow * 128 + col] = v;
                    if (WRB) Cb[(size_t)grow * 128 + col] = f2bf(v);
                }
            }
        }
        __syncthreads();   // protect sred reuse next iteration
    }
}

// ---------------------------------------------------------------------------
// Attention aggregation (R4 form — measured best: 55.7us, VGPR 32, occ 67%).
// 16-lanes-per-edge, 8 edges/iter. TLP at ~8 waves/SIMD hides gather latency;
// deeper per-wave unroll/prefetch measured WORSE (R2: 16-edge, R5: dbuf).
// ---------------------------------------------------------------------------
__global__ __launch_bounds__(256)
void agg_kernel(const unsigned short* qv, const unsigned short* __restrict__ kvv,
                const int* __restrict__ counts, const int* __restrict__ eslot,
                unsigned short* attn, int n_nodes)
{
    int w    = (int)((blockIdx.x * 256 + threadIdx.x) >> 6);
    int lane = threadIdx.x & 63;
    if (w >= n_nodes) return;
    const int g  = lane >> 4;   // edge slot within iteration
    const int li = lane & 15;   // 8-dim chunk; head = li>>1

    float qf[8];
    {
        uint4 qb = *(const uint4*)(qv + (size_t)w * 128 + li * 8);
        const unsigned* qp = (const unsigned*)&qb;
#pragma unroll
        for (int j = 0; j < 4; ++j) {
            qf[2 * j]     = bf2f((unsigned short)(qp[j] & 0xffff));
            qf[2 * j + 1] = bf2f((unsigned short)(qp[j] >> 16));
        }
    }

    const int beg = w << CAPLOG;
    const int end = beg + counts[w];
    float acc[8] = {0.f, 0.f, 0.f, 0.f, 0.f, 0.f, 0.f, 0.f};
    float z = 0.f;

    for (int e = beg; e < end; e += 8) {
        int  i0 = e + g;
        int  i1 = e + g + 4;
        bool v0 = i0 < end;
        bool v1 = i1 < end;
        int  s0 = eslot[v0 ? i0 : beg];
        int  s1 = eslot[v1 ? i1 : beg];

        const unsigned short* b0 = kvv + (size_t)s0 * 256 + li * 8;
        const unsigned short* b1 = kvv + (size_t)s1 * 256 + li * 8;
        uint4 kb0 = *(const uint4*)(b0);
        uint4 vb0 = *(const uint4*)(b0 + 128);
        uint4 kb1 = *(const uint4*)(b1);
        uint4 vb1 = *(const uint4*)(b1 + 128);

        const unsigned* kp0 = (const unsigned*)&kb0;
        const unsigned* kp1 = (const unsigned*)&kb1;
        float p0 = 0.f, p1 = 0.f;
#pragma unroll
        for (int j = 0; j < 4; ++j) {
            p0 = fmaf(bf2f((unsigned short)(kp0[j] & 0xffff)), qf[2 * j],     p0);
            p0 = fmaf(bf2f((unsigned short)(kp0[j] >> 16)),    qf[2 * j + 1], p0);
            p1 = fmaf(bf2f((unsigned short)(kp1[j] & 0xffff)), qf[2 * j],     p1);
            p1 = fmaf(bf2f((unsigned short)(kp1[j] >> 16)),    qf[2 * j + 1], p1);
        }
        p0 += __shfl_xor(p0, 1, 64);   // full 16-dim head score
        p1 += __shfl_xor(p1, 1, 64);

        float sv0 = __expf(fminf(fmaxf(p0 * 0.25f, -5.f), 5.f));
        float sv1 = __expf(fminf(fmaxf(p1 * 0.25f, -5.f), 5.f));
        sv0 = v0 ? sv0 : 0.f;
        sv1 = v1 ? sv1 : 0.f;

        const unsigned* vp0 = (const unsigned*)&vb0;
        const unsigned* vp1 = (const unsigned*)&vb1;
#pragma unroll
        for (int j = 0; j < 4; ++j) {
            acc[2 * j]     = fmaf(sv0, bf2f((unsigned short)(vp0[j] & 0xffff)), acc[2 * j]);
            acc[2 * j + 1] = fmaf(sv0, bf2f((unsigned short)(vp0[j] >> 16)),    acc[2 * j + 1]);
            acc[2 * j]     = fmaf(sv1, bf2f((unsigned short)(vp1[j] & 0xffff)), acc[2 * j]);
            acc[2 * j + 1] = fmaf(sv1, bf2f((unsigned short)(vp1[j] >> 16)),    acc[2 * j + 1]);
        }
        z += sv0 + sv1;
    }

#pragma unroll
    for (int o = 16; o < 64; o <<= 1) {
#pragma unroll
        for (int j = 0; j < 8; ++j) acc[j] += __shfl_xor(acc[j], o, 64);
        z += __shfl_xor(z, o, 64);
    }

    if (g == 0) {
        float inv = 1.f / (z + 1e-6f);
        unsigned ow[4];
#pragma unroll
        for (int j = 0; j < 4; ++j)
            ow[j] = (unsigned)f2bf(acc[2 * j] * inv) |
                    ((unsigned)f2bf(acc[2 * j + 1] * inv) << 16);
        *(uint4*)(attn + (size_t)w * 128 + li * 8) = *(const uint4*)ow;
    }
}

// ---------------------------------------------------------------------------
extern "C" void kernel_launch(void* const* d_in, const int* in_sizes, int n_in,
                              void* d_out, int out_size, void* d_ws, size_t ws_size,
                              hipStream_t stream)
{
    const float* h_in  = (const float*)d_in[0];
    const int*   src   = (const int*)d_in[1];
    const int*   dst   = (const int*)d_in[2];
    const float* W_emb = (const float*)d_in[3];
    const float* Wq    = (const float*)d_in[4];
    const float* bq    = (const float*)d_in[5];
    const float* Wk    = (const float*)d_in[6];
    const float* bk    = (const float*)d_in[7];
    const float* Wv    = (const float*)d_in[8];
    const float* bv    = (const float*)d_in[9];
    const float* Wo    = (const float*)d_in[10];
    const float* bo    = (const float*)d_in[11];
    const float* ln1w  = (const float*)d_in[12];
    const float* ln1b  = (const float*)d_in[13];
    const float* Wf1   = (const float*)d_in[14];
    const float* bf1   = (const float*)d_in[15];
    const float* Wf2   = (const float*)d_in[16];
    const float* bf2   = (const float*)d_in[17];
    const float* ln2w  = (const float*)d_in[18];
    const float* ln2b  = (const float*)d_in[19];
    float* out = (float*)d_out;

    const int N = N_NODES, E = N_EDGES;
    const size_t NF = (size_t)N * DMODEL;

    float*          hbuf  = (float*)d_ws;
    unsigned short* hbf   = (unsigned short*)(hbuf + NF);
    unsigned short* qbuf  = hbf + NF;
    unsigned short* kvbuf = qbuf + NF;        // [N][256]: K row | V row interleaved
    unsigned short* wf    = kvbuf + 2 * NF;
    int* counts = (int*)(wf + 278528);
    // padded edge buckets live in d_out: dead until layer-1's f2ln
    // (which completely overwrites it, after layer-1 agg consumed eslot).
    int* eslot  = (int*)d_out;
    unsigned short* fbuf = kvbuf;   // [N][256] bf16 FFN hidden (same footprint)

    const int EMB_O = 0, Q_O = 16384, K_O = 49152, V_O = 81920, O_O = 114688,
              F1_O = 147456, F2_O = 212992;

    const int GX = 391;   // 2 m-tiles/wave: measured-best point (R7/R11)

    // ---- weight prep + counts zeroing (y==13) ----
    PrepArgs pa;
    pa.seg[0]  = {W_emb,          128, 128, EMB_O};
    pa.seg[1]  = {Wq,             128, 128, Q_O};
    pa.seg[2]  = {Wq + 16384,     128, 128, Q_O + 16384};
    pa.seg[3]  = {Wk,             128, 128, K_O};
    pa.seg[4]  = {Wk + 16384,     128, 128, K_O + 16384};
    pa.seg[5]  = {Wv,             128, 128, V_O};
    pa.seg[6]  = {Wv + 16384,     128, 128, V_O + 16384};
    pa.seg[7]  = {Wo,             128, 128, O_O};
    pa.seg[8]  = {Wo + 16384,     128, 128, O_O + 16384};
    pa.seg[9]  = {Wf1,            128, 256, F1_O};
    pa.seg[10] = {Wf1 + 32768,    128, 256, F1_O + 32768};
    pa.seg[11] = {Wf2,            256, 128, F2_O};
    pa.seg[12] = {Wf2 + 32768,    256, 128, F2_O + 32768};
    prep_kernel<<<dim3(128, 14), 256, 0, stream>>>(pa, wf, counts);

    // ---- embedding GEMM + scatter half 1 (edges [0, ESPLIT)) ----
    emb_sc_gemm<<<dim3(GX, 2), 256, 0, stream>>>(
        h_in, wf + EMB_O, hbuf, hbf, MTILES, src, dst, counts, eslot, 0, ESPLIT);

    const int rowBlocks = (N + 3) / 4;
    for (int l = 0; l < 2; ++l) {
        // Q,K,V in one dispatch (+ scatter half 2 on layer 0)
        QkvPtrs qp;
        qp.bias[0] = bq + l * 128; qp.bias[1] = bk + l * 128; qp.bias[2] = bv + l * 128;
        qp.out[0] = qbuf;   qp.ldc[0] = 128;
        qp.out[1] = kvbuf;  qp.ldc[1] = 256;
        qp.out[2] = kvbuf + 128; qp.ldc[2] = 256;
        qkv_sc_gemm<<<dim3(GX, l == 0 ? 4 : 3), 256, 0, stream>>>(
            hbf, wf + Q_O + l * 16384, qp, MTILES, src, dst, counts, eslot,
            l == 0 ? ESPLIT : 0, l == 0 ? E : 0);

        // attention aggregate (attn aliases qbuf)
        agg_kernel<<<rowBlocks, 256, 0, stream>>>(qbuf, kvbuf, counts, eslot, qbuf, N);

        // hx = LN1(h + attn @ Wo + bo)  [fused GEMM+residual+LN] -> hbuf + hbf
        mfma_gemm<4, 8, 3, false, true, true><<<dim3(GX, 1), 256, 0, stream>>>(
            qbuf, wf + O_O + l * 16384, bo + l * 128, hbuf, hbuf, hbf,
            ln1w + l * 128, ln1b + l * 128, 128, 128, MTILES);

        // f1 = relu(hx @ Wf1 + bf1) -> bf16 [N,256]
        mfma_gemm<4, 8, 1, false, false, true><<<dim3(GX, 2), 256, 0, stream>>>(
            hbf, wf + F1_O + l * 32768, bf1 + l * 256, nullptr, nullptr, fbuf,
            nullptr, nullptr, 128, 256, MTILES);

        // h = LN2(hx + f1 @ Wf2 + bf2)  [fused, wave-pair NT-split]
        if (l == 0)
            f2ln_kernel<true><<<dim3(GX, 1), 256, 0, stream>>>(
                fbuf, wf + F2_O, bf2, hbuf, hbuf, hbf, ln2w, ln2b, MTILES);
        else
            f2ln_kernel<false><<<dim3(GX, 1), 256, 0, stream>>>(
                fbuf, wf + F2_O + 32768, bf2 + 128, hbuf, out, nullptr,
                ln2w + 128, ln2b + 128, MTILES);
    }
}

// Round 13
// 394.683 us; speedup vs baseline: 1.1555x; 1.0377x over previous
//
#include <hip/hip_runtime.h>
#include <math.h>

static constexpr int N_NODES = 50000;
static constexpr int N_EDGES = 800000;
static constexpr int DMODEL  = 128;
static constexpr int MTILES  = N_NODES / 16;   // 3125 exactly
static constexpr int CAPLOG  = 6;              // 64 slots/node; max degree ~40 (Poisson(16))
static constexpr int ESPLIT  = 400384;         // scatter split point

typedef __attribute__((ext_vector_type(8))) short short8;   // 8 bf16 (4 VGPRs)
typedef __attribute__((ext_vector_type(4))) float float4v;  // 4 fp32 acc

__device__ __forceinline__ unsigned short f2bf(float f) {
    unsigned u = __builtin_bit_cast(unsigned, f);
    u += 0x7fffu + ((u >> 16) & 1u);
    return (unsigned short)(u >> 16);
}
__device__ __forceinline__ float bf2f(unsigned short b) {
    unsigned u = ((unsigned)b) << 16;
    return __builtin_bit_cast(float, u);
}

// ---------------------------------------------------------------------------
// Weight prep: fp32 [K][N] row-major -> bf16 MFMA B-fragment order.
//   idx = (nt*ksteps + s)*512 + quad*128 + c*8 + j   (nt=n>>4, c=n&15, s=k>>5)
// blockIdx.y==13 zeroes the counts array (replaces the memset dispatch).
// ---------------------------------------------------------------------------
struct PrepSeg { const float* src; int K; int N; int dstOff; };
struct PrepArgs { PrepSeg seg[13]; };

__global__ void prep_kernel(PrepArgs pa, unsigned short* wf, int* counts)
{
    if (blockIdx.y == 13) {
        for (int i = blockIdx.x * 256 + threadIdx.x; i < N_NODES; i += 128 * 256)
            counts[i] = 0;
        return;
    }
    PrepSeg sg = pa.seg[blockIdx.y];
    int e = blockIdx.x * 256 + threadIdx.x;
    int total = sg.K * sg.N;
    if (e >= total) return;
    int n = e % sg.N;
    int k = e / sg.N;
    int ks = sg.K >> 5;
    int nt = n >> 4, c = n & 15, s = k >> 5, q = (k >> 3) & 3, jj = k & 7;
    int di = sg.dstOff + (nt * ks + s) * 512 + q * 128 + c * 8 + jj;
    wf[di] = f2bf(sg.src[e]);
}

// ---------------------------------------------------------------------------
// Padded one-pass bucket build body: rank = atomicAdd(counts[dst]), slot into
// eslot[dst*64 + rank]. Fused into GEMM dispatches (extra blockIdx.y
// partition). Blocks whose whole range is past eend exit immediately.
// ---------------------------------------------------------------------------
__device__ __forceinline__ void scatter_body(
    const int* __restrict__ src, const int* __restrict__ dst,
    int* counts, int* eslot, int ebeg, int eend)
{
    int blk = ebeg + blockIdx.x * 1024;
    if (blk >= eend) return;
    int base = blk + threadIdx.x;
    int d[4], s[4];
    bool v[4];
#pragma unroll
    for (int k = 0; k < 4; ++k) {
        int e = base + k * 256;
        v[k] = e < eend;
        int ec = v[k] ? e : ebeg;
        d[k] = dst[ec];
        s[k] = src[ec];
    }
#pragma unroll
    for (int k = 0; k < 4; ++k) {
        if (v[k]) {
            int r = atomicAdd(&counts[d[k]], 1);
            eslot[(d[k] << CAPLOG) + r] = s[k];
        }
    }
}

// ---------------------------------------------------------------------------
// MFMA GEMM body with LDS-staged B (R8 win; GX=391 = 2 m-tiles/wave is the
// measured-best operating point — R7/R11 showed 1 tile/wave loses to
// per-block fixed costs regardless of B source).
// EPI: 0=bias, 1=bias+relu, 2=bias+residual, 3=bias+residual+LayerNorm
// (EPI 3 requires NT*16==128, colBase==0).
// ---------------------------------------------------------------------------
template<int KSTEPS, int NT, int EPI, bool AF32, bool WRF, bool WRB>
__device__ __forceinline__ void gemm_body(
    const void* __restrict__ Ap, const unsigned short* __restrict__ Wfc,
    const float* __restrict__ bias, const float* res,
    float* Cf, unsigned short* Cb,
    const float* __restrict__ lnw, const float* __restrict__ lnb,
    int ldA, int ldC, int mtiles, int colBase)
{
    const int lane = threadIdx.x & 63;
    const int c = lane & 15;
    const int q = lane >> 4;

    // ---- cooperative B-panel stage ----
    __shared__ unsigned short smB[NT * KSTEPS * 512];
    {
        const int totalVec = NT * KSTEPS * 64;   // uint4 count
        const uint4* gsrc = (const uint4*)Wfc;
        uint4* sdst = (uint4*)smB;
#pragma unroll
        for (int i = threadIdx.x; i < totalVec; i += 256)
            sdst[i] = gsrc[i];
    }
    __syncthreads();

    short8 bfrag[NT][KSTEPS];
#pragma unroll
    for (int nt = 0; nt < NT; ++nt)
#pragma unroll
        for (int s = 0; s < KSTEPS; ++s)
            bfrag[nt][s] = *(const short8*)(smB + (nt * KSTEPS + s) * 512 + lane * 8);

    float bb[NT];
#pragma unroll
    for (int nt = 0; nt < NT; ++nt)
        bb[nt] = bias ? bias[colBase + nt * 16 + c] : 0.f;

    float lw[NT], lb[NT];
    if (EPI == 3) {
#pragma unroll
        for (int nt = 0; nt < NT; ++nt) {
            lw[nt] = lnw[nt * 16 + c];
            lb[nt] = lnb[nt * 16 + c];
        }
    }

    const int wid = blockIdx.x * 4 + (threadIdx.x >> 6);
    const int nw  = gridDim.x * 4;

    for (int mt = wid; mt < mtiles; mt += nw) {
        const int row0 = mt * 16;
        short8 afrag[KSTEPS];
        if (AF32) {
            const float* A32 = (const float*)Ap;
#pragma unroll
            for (int s = 0; s < KSTEPS; ++s) {
                const float4* p = (const float4*)(A32 + (size_t)(row0 + c) * ldA + s * 32 + q * 8);
                float4 x0 = p[0], x1 = p[1];
                short8 a;
                a[0] = (short)f2bf(x0.x); a[1] = (short)f2bf(x0.y);
                a[2] = (short)f2bf(x0.z); a[3] = (short)f2bf(x0.w);
                a[4] = (short)f2bf(x1.x); a[5] = (short)f2bf(x1.y);
                a[6] = (short)f2bf(x1.z); a[7] = (short)f2bf(x1.w);
                afrag[s] = a;
            }
        } else {
            const unsigned short* Ab = (const unsigned short*)Ap;
#pragma unroll
            for (int s = 0; s < KSTEPS; ++s)
                afrag[s] = *(const short8*)(Ab + (size_t)(row0 + c) * ldA + s * 32 + q * 8);
        }

        float4v acc[NT];
#pragma unroll
        for (int nt = 0; nt < NT; ++nt) acc[nt] = (float4v)0.f;
#pragma unroll
        for (int s = 0; s < KSTEPS; ++s)
#pragma unroll
            for (int nt = 0; nt < NT; ++nt)
                acc[nt] = __builtin_amdgcn_mfma_f32_16x16x32_bf16(afrag[s], bfrag[nt][s], acc[nt], 0, 0, 0);

        // epilogue: C row = row0 + q*4 + r, col = colBase + nt*16 + c
#pragma unroll
        for (int nt = 0; nt < NT; ++nt) {
            const int col = colBase + nt * 16 + c;
#pragma unroll
            for (int r = 0; r < 4; ++r) {
                const int grow = row0 + q * 4 + r;
                float v = acc[nt][r] + bb[nt];
                if (EPI == 2 || EPI == 3) v += res[(size_t)grow * ldC + col];
                if (EPI == 1) v = fmaxf(v, 0.f);
                acc[nt][r] = v;
            }
        }

        if (EPI == 3) {
#pragma unroll
            for (int r = 0; r < 4; ++r) {
                float s = 0.f, ss = 0.f;
#pragma unroll
                for (int nt = 0; nt < NT; ++nt) {
                    float v = acc[nt][r];
                    s += v; ss = fmaf(v, v, ss);
                }
#pragma unroll
                for (int o = 1; o < 16; o <<= 1) {
                    s  += __shfl_xor(s, o, 64);
                    ss += __shfl_xor(ss, o, 64);
                }
                float m   = s * (1.0f / 128.0f);
                float var = ss * (1.0f / 128.0f) - m * m;
                float rs  = rsqrtf(var + 1e-5f);
                const int grow = row0 + q * 4 + r;
#pragma unroll
                for (int nt = 0; nt < NT; ++nt) {
                    float v = (acc[nt][r] - m) * rs * lw[nt] + lb[nt];
                    if (WRF) Cf[(size_t)grow * ldC + nt * 16 + c] = v;
                    if (WRB) Cb[(size_t)grow * ldC + nt * 16 + c] = f2bf(v);
                }
            }
        } else {
#pragma unroll
            for (int nt = 0; nt < NT; ++nt) {
                const int col = colBase + nt * 16 + c;
#pragma unroll
                for (int r = 0; r < 4; ++r) {
                    const int grow = row0 + q * 4 + r;
                    if (WRF) Cf[(size_t)grow * ldC + col] = acc[nt][r];
                    if (WRB) Cb[(size_t)grow * ldC + col] = f2bf(acc[nt][r]);
                }
            }
        }
    }
}

template<int KSTEPS, int NT, int EPI, bool AF32, bool WRF, bool WRB>
__global__ __launch_bounds__(256, 2)
void mfma_gemm(const void* __restrict__ Ap, const unsigned short* __restrict__ Wf,
               const float* __restrict__ bias, const float* res,
               float* Cf, unsigned short* Cb,
               const float* __restrict__ lnw, const float* __restrict__ lnb,
               int ldA, int ldC, int mtiles)
{
    const int colBase = blockIdx.y * NT * 16;
    const unsigned short* Wfc = Wf + (size_t)blockIdx.y * NT * KSTEPS * 512;
    gemm_body<KSTEPS, NT, EPI, AF32, WRF, WRB>(
        Ap, Wfc, bias, res, Cf, Cb, lnw, lnb, ldA, ldC, mtiles, colBase);
}

// Embedding GEMM fused with scatter half 1 (blockIdx.y==1 -> scatter).
__global__ __launch_bounds__(256, 2)
void emb_sc_gemm(const float* __restrict__ A, const unsigned short* __restrict__ Wf,
                 float* Cf, unsigned short* Cb, int mtiles,
                 const int* __restrict__ src, const int* __restrict__ dst,
                 int* counts, int* eslot, int ebeg, int eend)
{
    if (blockIdx.y == 1) {
        scatter_body(src, dst, counts, eslot, ebeg, eend);
        return;
    }
    gemm_body<4, 8, 0, true, true, true>(
        A, Wf, nullptr, nullptr, Cf, Cb, nullptr, nullptr, 128, 128, mtiles, 0);
}

// Q/K/V fused + scatter half 2 (blockIdx.y==3 -> scatter on layer 0).
// K and V write into the interleaved kv buffer [node][K 0..127 | V 128..255].
struct QkvPtrs { const float* bias[3]; unsigned short* out[3]; int ldc[3]; };

__global__ __launch_bounds__(256, 2)
void qkv_sc_gemm(const unsigned short* __restrict__ A, const unsigned short* __restrict__ WfBase,
                 QkvPtrs ptrs, int mtiles,
                 const int* __restrict__ src, const int* __restrict__ dst,
                 int* counts, int* eslot, int ebeg, int eend)
{
    if (blockIdx.y == 3) {
        scatter_body(src, dst, counts, eslot, ebeg, eend);
        return;
    }
    const int sel = blockIdx.y;
    gemm_body<4, 8, 0, false, false, true>(
        A, WfBase + (size_t)sel * 32768, ptrs.bias[sel], nullptr,
        nullptr, ptrs.out[sel], nullptr, nullptr, 128, ptrs.ldc[sel], mtiles, 0);
}

// ---------------------------------------------------------------------------
// Fully fused FFN: h = LN2(hx + relu(hx@Wf1 + bf1)@Wf2 + bf2).
// Replaces f1 GEMM + f2ln per layer; deletes the 51MB/layer fbuf round-trip.
// Block = 4 waves cooperating on ONE 16-row tile per iteration:
//   stage 1: wave w computes f1 cols [64w,64w+64)  (B1 = 4nt x 4ks regs)
//   exchange: relu'd 16x256 tile -> 8KB LDS in stage-2 A-FRAG ORDER
//             exf[s][lane][j] so stage-2 reads are lane-sequential b128
//   stage 2: wave w computes f2 cols [32w,32w+32)  (B2 = 2nt x 8ks regs)
//            + residual + 4-way sred LN (proven f2ln pattern).
// 2 uniform barriers/iter; inactive tail tiles masked (row0=0, no writes).
// hbf read-before-write within each iteration is barrier-ordered.
// ---------------------------------------------------------------------------
template<bool WRB>
__global__ __launch_bounds__(256, 2)
void ffn_kernel(const unsigned short* __restrict__ A,     // hbf [N][128] bf16 (hx)
                const unsigned short* __restrict__ W1,    // Wf1 frags (ks=4, nt 0..15)
                const unsigned short* __restrict__ W2,    // Wf2 frags (ks=8, nt 0..7)
                const float* __restrict__ b1, const float* __restrict__ b2,
                const float* __restrict__ res,            // hbuf fp32 (hx)
                float* Cf, unsigned short* Cb,
                const float* __restrict__ lnw, const float* __restrict__ lnb,
                int mtiles)
{
    const int lane = threadIdx.x & 63;
    const int c = lane & 15;
    const int q = lane >> 4;
    const int w = threadIdx.x >> 6;   // 0..3

    __shared__ unsigned short exf[8 * 64 * 8];   // [s2][lane][j], 8KB
    __shared__ float sred[16][4][2];             // [row][wave][s,ss]

    short8 b1f[4][4];
#pragma unroll
    for (int nt = 0; nt < 4; ++nt)
#pragma unroll
        for (int s = 0; s < 4; ++s)
            b1f[nt][s] = *(const short8*)(W1 + (size_t)((w * 4 + nt) * 4 + s) * 512 + lane * 8);

    short8 b2f[2][8];
#pragma unroll
    for (int nt = 0; nt < 2; ++nt)
#pragma unroll
        for (int s = 0; s < 8; ++s)
            b2f[nt][s] = *(const short8*)(W2 + (size_t)((w * 2 + nt) * 8 + s) * 512 + lane * 8);

    float bb1[4];
#pragma unroll
    for (int nt = 0; nt < 4; ++nt) bb1[nt] = b1[w * 64 + nt * 16 + c];
    float bb2[2], lw[2], lb[2];
#pragma unroll
    for (int nt = 0; nt < 2; ++nt) {
        int col = w * 32 + nt * 16 + c;
        bb2[nt] = b2[col]; lw[nt] = lnw[col]; lb[nt] = lnb[col];
    }

    const int iters = (mtiles + gridDim.x - 1) / gridDim.x;
    for (int it = 0; it < iters; ++it) {
        const int mt = blockIdx.x + it * gridDim.x;
        const bool active = mt < mtiles;
        const int row0 = (active ? mt : 0) * 16;

        // ---- stage 1: f1 cols [64w, 64w+64) ----
        short8 af[4];
#pragma unroll
        for (int s = 0; s < 4; ++s)
            af[s] = *(const short8*)(A + (size_t)(row0 + c) * 128 + s * 32 + q * 8);

        float4v acc1[4];
#pragma unroll
        for (int nt = 0; nt < 4; ++nt) acc1[nt] = (float4v)0.f;
#pragma unroll
        for (int s = 0; s < 4; ++s)
#pragma unroll
            for (int nt = 0; nt < 4; ++nt)
                acc1[nt] = __builtin_amdgcn_mfma_f32_16x16x32_bf16(af[s], b1f[nt][s], acc1[nt], 0, 0, 0);

        // relu+bias -> exf in stage-2 A-frag order:
        // value at (row=q*4+r, col=64w+16nt+c): s2=col>>5, q2=(col>>3)&3,
        // j=col&7, c2=row -> exf[((s2*4+q2)*16 + c2)*8 + j]
#pragma unroll
        for (int nt = 0; nt < 4; ++nt) {
            const int col = w * 64 + nt * 16 + c;
            const int base = ((col >> 5) * 4 + ((col >> 3) & 3)) * 16;
            const int j = col & 7;
#pragma unroll
            for (int r = 0; r < 4; ++r) {
                float v = fmaxf(acc1[nt][r] + bb1[nt], 0.f);
                exf[(size_t)(base + q * 4 + r) * 8 + j] = f2bf(v);
            }
        }
        __syncthreads();

        // ---- stage 2: f2 cols [32w, 32w+32) ----
        short8 af2[8];
#pragma unroll
        for (int s = 0; s < 8; ++s)
            af2[s] = *(const short8*)(exf + (size_t)(s * 64 + lane) * 8);

        float4v acc2[2];
#pragma unroll
        for (int nt = 0; nt < 2; ++nt) acc2[nt] = (float4v)0.f;
#pragma unroll
        for (int s = 0; s < 8; ++s)
#pragma unroll
            for (int nt = 0; nt < 2; ++nt)
                acc2[nt] = __builtin_amdgcn_mfma_f32_16x16x32_bf16(af2[s], b2f[nt][s], acc2[nt], 0, 0, 0);

        float vv[2][4];
#pragma unroll
        for (int nt = 0; nt < 2; ++nt)
#pragma unroll
            for (int r = 0; r < 4; ++r)
                vv[nt][r] = acc2[nt][r] + bb2[nt] +
                            res[(size_t)(row0 + q * 4 + r) * 128 + w * 32 + nt * 16 + c];

        // per-row partials over this wave's 32 cols -> sred
#pragma unroll
        for (int r = 0; r < 4; ++r) {
            float s  = vv[0][r] + vv[1][r];
            float ss = fmaf(vv[0][r], vv[0][r], vv[1][r] * vv[1][r]);
#pragma unroll
            for (int o = 1; o < 16; o <<= 1) {
                s  += __shfl_xor(s, o, 64);
                ss += __shfl_xor(ss, o, 64);
            }
            if (c == 0) {
                sred[q * 4 + r][w][0] = s;
                sred[q * 4 + r][w][1] = ss;
            }
        }
        __syncthreads();

#pragma unroll
        for (int r = 0; r < 4; ++r) {
            const int rr = q * 4 + r;
            float S  = sred[rr][0][0] + sred[rr][1][0] + sred[rr][2][0] + sred[rr][3][0];
            float SS = sred[rr][0][1] + sred[rr][1][1] + sred[rr][2][1] + sred[rr][3][1];
            float m   = S * (1.0f / 128.0f);
            float var = SS * (1.0f / 128.0f) - m * m;
            float rs  = rsqrtf(var + 1e-5f);
            if (active) {
                const int grow = row0 + rr;
#pragma unroll
                for (int nt = 0; nt < 2; ++nt) {
                    const int col = w * 32 + nt * 16 + c;
                    float v = (vv[nt][r] - m) * rs * lw[nt] + lb[nt];
                    Cf[(size_t)grow * 128 + col] = v;
                    if (WRB) Cb[(size_t)grow * 128 + col] = f2bf(v);
                }
            }
        }
        // next iteration's bar1 (after exf write) orders sred reads vs rewrite
    }
}

// ---------------------------------------------------------------------------
// Attention aggregation (R4 form — measured best: 55.7us, VGPR 32, occ 67%).
// 16-lanes-per-edge, 8 edges/iter. TLP at ~8 waves/SIMD hides gather latency;
// deeper per-wave unroll/prefetch measured WORSE (R2: 16-edge, R5: dbuf).
// ---------------------------------------------------------------------------
__global__ __launch_bounds__(256)
void agg_kernel(const unsigned short* qv, const unsigned short* __restrict__ kvv,
                const int* __restrict__ counts, const int* __restrict__ eslot,
                unsigned short* attn, int n_nodes)
{
    int w    = (int)((blockIdx.x * 256 + threadIdx.x) >> 6);
    int lane = threadIdx.x & 63;
    if (w >= n_nodes) return;
    const int g  = lane >> 4;   // edge slot within iteration
    const int li = lane & 15;   // 8-dim chunk; head = li>>1

    float qf[8];
    {
        uint4 qb = *(const uint4*)(qv + (size_t)w * 128 + li * 8);
        const unsigned* qp = (const unsigned*)&qb;
#pragma unroll
        for (int j = 0; j < 4; ++j) {
            qf[2 * j]     = bf2f((unsigned short)(qp[j] & 0xffff));
            qf[2 * j + 1] = bf2f((unsigned short)(qp[j] >> 16));
        }
    }

    const int beg = w << CAPLOG;
    const int end = beg + counts[w];
    float acc[8] = {0.f, 0.f, 0.f, 0.f, 0.f, 0.f, 0.f, 0.f};
    float z = 0.f;

    for (int e = beg; e < end; e += 8) {
        int  i0 = e + g;
        int  i1 = e + g + 4;
        bool v0 = i0 < end;
        bool v1 = i1 < end;
        int  s0 = eslot[v0 ? i0 : beg];
        int  s1 = eslot[v1 ? i1 : beg];

        const unsigned short* b0 = kvv + (size_t)s0 * 256 + li * 8;
        const unsigned short* b1 = kvv + (size_t)s1 * 256 + li * 8;
        uint4 kb0 = *(const uint4*)(b0);
        uint4 vb0 = *(const uint4*)(b0 + 128);
        uint4 kb1 = *(const uint4*)(b1);
        uint4 vb1 = *(const uint4*)(b1 + 128);

        const unsigned* kp0 = (const unsigned*)&kb0;
        const unsigned* kp1 = (const unsigned*)&kb1;
        float p0 = 0.f, p1 = 0.f;
#pragma unroll
        for (int j = 0; j < 4; ++j) {
            p0 = fmaf(bf2f((unsigned short)(kp0[j] & 0xffff)), qf[2 * j],     p0);
            p0 = fmaf(bf2f((unsigned short)(kp0[j] >> 16)),    qf[2 * j + 1], p0);
            p1 = fmaf(bf2f((unsigned short)(kp1[j] & 0xffff)), qf[2 * j],     p1);
            p1 = fmaf(bf2f((unsigned short)(kp1[j] >> 16)),    qf[2 * j + 1], p1);
        }
        p0 += __shfl_xor(p0, 1, 64);   // full 16-dim head score
        p1 += __shfl_xor(p1, 1, 64);

        float sv0 = __expf(fminf(fmaxf(p0 * 0.25f, -5.f), 5.f));
        float sv1 = __expf(fminf(fmaxf(p1 * 0.25f, -5.f), 5.f));
        sv0 = v0 ? sv0 : 0.f;
        sv1 = v1 ? sv1 : 0.f;

        const unsigned* vp0 = (const unsigned*)&vb0;
        const unsigned* vp1 = (const unsigned*)&vb1;
#pragma unroll
        for (int j = 0; j < 4; ++j) {
            acc[2 * j]     = fmaf(sv0, bf2f((unsigned short)(vp0[j] & 0xffff)), acc[2 * j]);
            acc[2 * j + 1] = fmaf(sv0, bf2f((unsigned short)(vp0[j] >> 16)),    acc[2 * j + 1]);
            acc[2 * j]     = fmaf(sv1, bf2f((unsigned short)(vp1[j] & 0xffff)), acc[2 * j]);
            acc[2 * j + 1] = fmaf(sv1, bf2f((unsigned short)(vp1[j] >> 16)),    acc[2 * j + 1]);
        }
        z += sv0 + sv1;
    }

#pragma unroll
    for (int o = 16; o < 64; o <<= 1) {
#pragma unroll
        for (int j = 0; j < 8; ++j) acc[j] += __shfl_xor(acc[j], o, 64);
        z += __shfl_xor(z, o, 64);
    }

    if (g == 0) {
        float inv = 1.f / (z + 1e-6f);
        unsigned ow[4];
#pragma unroll
        for (int j = 0; j < 4; ++j)
            ow[j] = (unsigned)f2bf(acc[2 * j] * inv) |
                    ((unsigned)f2bf(acc[2 * j + 1] * inv) << 16);
        *(uint4*)(attn + (size_t)w * 128 + li * 8) = *(const uint4*)ow;
    }
}

// ---------------------------------------------------------------------------
extern "C" void kernel_launch(void* const* d_in, const int* in_sizes, int n_in,
                              void* d_out, int out_size, void* d_ws, size_t ws_size,
                              hipStream_t stream)
{
    const float* h_in  = (const float*)d_in[0];
    const int*   src   = (const int*)d_in[1];
    const int*   dst   = (const int*)d_in[2];
    const float* W_emb = (const float*)d_in[3];
    const float* Wq    = (const float*)d_in[4];
    const float* bq    = (const float*)d_in[5];
    const float* Wk    = (const float*)d_in[6];
    const float* bk    = (const float*)d_in[7];
    const float* Wv    = (const float*)d_in[8];
    const float* bv    = (const float*)d_in[9];
    const float* Wo    = (const float*)d_in[10];
    const float* bo    = (const float*)d_in[11];
    const float* ln1w  = (const float*)d_in[12];
    const float* ln1b  = (const float*)d_in[13];
    const float* Wf1   = (const float*)d_in[14];
    const float* bf1   = (const float*)d_in[15];
    const float* Wf2   = (const float*)d_in[16];
    const float* bf2   = (const float*)d_in[17];
    const float* ln2w  = (const float*)d_in[18];
    const float* ln2b  = (const float*)d_in[19];
    float* out = (float*)d_out;

    const int N = N_NODES, E = N_EDGES;
    const size_t NF = (size_t)N * DMODEL;

    float*          hbuf  = (float*)d_ws;
    unsigned short* hbf   = (unsigned short*)(hbuf + NF);
    unsigned short* qbuf  = hbf + NF;
    unsigned short* kvbuf = qbuf + NF;        // [N][256]: K row | V row interleaved
    unsigned short* wf    = kvbuf + 2 * NF;
    int* counts = (int*)(wf + 278528);
    // padded edge buckets live in d_out: dead until layer-1's ffn_kernel
    // (which completely overwrites it, after layer-1 agg consumed eslot).
    int* eslot  = (int*)d_out;

    const int EMB_O = 0, Q_O = 16384, K_O = 49152, V_O = 81920, O_O = 114688,
              F1_O = 147456, F2_O = 212992;

    const int GX = 391;   // 2 m-tiles/wave: measured-best point (R7/R11)

    // ---- weight prep + counts zeroing (y==13) ----
    PrepArgs pa;
    pa.seg[0]  = {W_emb,          128, 128, EMB_O};
    pa.seg[1]  = {Wq,             128, 128, Q_O};
    pa.seg[2]  = {Wq + 16384,     128, 128, Q_O + 16384};
    pa.seg[3]  = {Wk,             128, 128, K_O};
    pa.seg[4]  = {Wk + 16384,     128, 128, K_O + 16384};
    pa.seg[5]  = {Wv,             128, 128, V_O};
    pa.seg[6]  = {Wv + 16384,     128, 128, V_O + 16384};
    pa.seg[7]  = {Wo,             128, 128, O_O};
    pa.seg[8]  = {Wo + 16384,     128, 128, O_O + 16384};
    pa.seg[9]  = {Wf1,            128, 256, F1_O};
    pa.seg[10] = {Wf1 + 32768,    128, 256, F1_O + 32768};
    pa.seg[11] = {Wf2,            256, 128, F2_O};
    pa.seg[12] = {Wf2 + 32768,    256, 128, F2_O + 32768};
    prep_kernel<<<dim3(128, 14), 256, 0, stream>>>(pa, wf, counts);

    // ---- embedding GEMM + scatter half 1 (edges [0, ESPLIT)) ----
    emb_sc_gemm<<<dim3(GX, 2), 256, 0, stream>>>(
        h_in, wf + EMB_O, hbuf, hbf, MTILES, src, dst, counts, eslot, 0, ESPLIT);

    const int rowBlocks = (N + 3) / 4;
    for (int l = 0; l < 2; ++l) {
        // Q,K,V in one dispatch (+ scatter half 2 on layer 0)
        QkvPtrs qp;
        qp.bias[0] = bq + l * 128; qp.bias[1] = bk + l * 128; qp.bias[2] = bv + l * 128;
        qp.out[0] = qbuf;   qp.ldc[0] = 128;
        qp.out[1] = kvbuf;  qp.ldc[1] = 256;
        qp.out[2] = kvbuf + 128; qp.ldc[2] = 256;
        qkv_sc_gemm<<<dim3(GX, l == 0 ? 4 : 3), 256, 0, stream>>>(
            hbf, wf + Q_O + l * 16384, qp, MTILES, src, dst, counts, eslot,
            l == 0 ? ESPLIT : 0, l == 0 ? E : 0);

        // attention aggregate (attn aliases qbuf)
        agg_kernel<<<rowBlocks, 256, 0, stream>>>(qbuf, kvbuf, counts, eslot, qbuf, N);

        // hx = LN1(h + attn @ Wo + bo)  [fused GEMM+residual+LN] -> hbuf + hbf
        mfma_gemm<4, 8, 3, false, true, true><<<dim3(GX, 1), 256, 0, stream>>>(
            qbuf, wf + O_O + l * 16384, bo + l * 128, hbuf, hbuf, hbf,
            ln1w + l * 128, ln1b + l * 128, 128, 128, MTILES);

        // h = LN2(hx + relu(hx@Wf1+bf1)@Wf2 + bf2)  [fully fused FFN]
        if (l == 0)
            ffn_kernel<true><<<dim3(GX, 1), 256, 0, stream>>>(
                hbf, wf + F1_O, wf + F2_O, bf1, bf2,
                hbuf, hbuf, hbf, ln2w, ln2b, MTILES);
        else
            ffn_kernel<false><<<dim3(GX, 1), 256, 0, stream>>>(
                hbf, wf + F1_O + 32768, wf + F2_O + 32768, bf1 + 256, bf2 + 128,
                hbuf, out, nullptr, ln2w + 128, ln2b + 128, MTILES);
    }
}